// Round 1
// baseline (160.877 us; speedup 1.0000x reference)
//
#include <hip/hip_runtime.h>

typedef _Float16 f16;
typedef f16 f16x8 __attribute__((ext_vector_type(8)));
typedef f16 f16x4 __attribute__((ext_vector_type(4)));
typedef float f32x4 __attribute__((ext_vector_type(4)));

#define MFMA16(a, b, c) __builtin_amdgcn_mfma_f32_16x16x32_f16(a, b, c, 0, 0, 0)

// packed-weight offsets in f16 elements within d_ws
#define OFF_RW1A 0
#define OFF_RW2  10240
#define OFF_RW3  35840
#define OFF_QW1  46080
#define OFF_QW2  87040
#define OFF_QW3  112640
#define OFF_PW1  122880
#define OFF_PW2  163840
#define OFF_PW3  189440
#define PACK_BYTES 399360   // 199680 f16

struct InPtrs { const float* p[21]; };

// ---------------------------------------------------------------------------
// prep: blocks 0..98 pack 9 weight matrices into MFMA B-fragment layout (f16),
//       block 99 = Qmax, block 100 = e1q, blocks 101..356 = c1/d1,
//       blocks 357..1380 = red0 (max over i of R).
// ---------------------------------------------------------------------------
__global__ __launch_bounds__(256) void prep_kernel(InPtrs in, f16* __restrict__ wpk,
    float* __restrict__ c1, float* __restrict__ d1, float* __restrict__ e1q,
    float* __restrict__ qmax, float* __restrict__ red0)
{
  __shared__ float sbuf[4][128];
  const int mb = blockIdx.x, t = threadIdx.x;

  if (mb < 99) {
    const int mSrc[9] = {15, 17, 19, 9, 11, 13, 3, 5, 7};
    const int mK0[9]  = {0, 0, 0, 128, 0, 0, 0, 0, 0};
    const int mK[9]   = {64, 132, 132, 256, 132, 132, 256, 132, 132};
    const int mN[9]   = {132, 132, 64, 132, 132, 64, 132, 132, 64};
    const int mKT[9]  = {2, 5, 5, 8, 5, 5, 8, 5, 5};
    const int mNT[9]  = {10, 10, 4, 10, 10, 4, 10, 10, 4};
    const int mDst[9] = {OFF_RW1A, OFF_RW2, OFF_RW3, OFF_QW1, OFF_QW2, OFF_QW3,
                         OFF_PW1, OFF_PW2, OFF_PW3};
    const int mBlk0[9] = {0, 5, 18, 23, 43, 56, 61, 81, 94};
    int mi = 8;
    while (mi > 0 && mb < mBlk0[mi]) --mi;
    const int L = (mb - mBlk0[mi]) * 256 + t;
    const int lanes = mKT[mi] * mNT[mi] * 64;
    if (L < lanes) {
      const int lane = L & 63, tile = L >> 6;
      const int kk = tile / mNT[mi], nn = tile % mNT[mi];
      const float* src = in.p[mSrc[mi]];
      const int n = nn * 16 + (lane & 15);
      const int kb = kk * 32 + ((lane >> 4) << 3);
      f16x8 v;
      #pragma unroll
      for (int u = 0; u < 8; ++u) {
        const int k = kb + u;
        float f = (k < mK[mi] && n < mN[mi]) ? src[(size_t)(mK0[mi] + k) * mN[mi] + n] : 0.f;
        v[u] = (f16)f;
      }
      *(f16x8*)(wpk + mDst[mi] + (size_t)L * 8) = v;
    }
  } else if (mb == 99) {            // Qmax[b,d] = max_i Q[b,i,d]
    const float* Q = in.p[1];
    for (int o = t; o < 1024; o += 256) {
      const int b = o >> 7, d = o & 127;
      float m = -3.4e38f;
      for (int i = 0; i < 128; ++i) m = fmaxf(m, Q[(size_t)(b * 128 + i) * 128 + d]);
      qmax[b * 128 + d] = m;
    }
  } else if (mb == 100) {           // e1q[b,n] = P[b] . q_w1[0:128] + q_b1
    const float* P = in.p[0]; const float* qw1 = in.p[9]; const float* qb1 = in.p[10];
    if (t < 160) {
      for (int b = 0; b < 8; ++b) {
        float a = 0.f;
        if (t < 132) {
          a = qb1[t];
          for (int k = 0; k < 128; ++k) a += P[b * 128 + k] * qw1[(size_t)k * 132 + t];
        }
        e1q[b * 160 + t] = a;
      }
    }
  } else if (mb < 357) {            // c1/d1 (r-branch folded Q contributions), 4 rows/block
    const int blk = mb - 101;
    const float* Q = in.p[1]; const float* rw1 = in.p[15]; const float* rb1 = in.p[16];
    for (int o = t; o < 512; o += 256) sbuf[o >> 7][o & 127] = Q[(size_t)blk * 512 + o];
    __syncthreads();
    if (t < 160) {
      float cc[4], dd[4];
      #pragma unroll
      for (int r = 0; r < 4; ++r) { cc[r] = 0.f; dd[r] = 0.f; }
      if (t < 132) {
        const float bb = rb1[t];
        #pragma unroll
        for (int r = 0; r < 4; ++r) cc[r] = bb;
        for (int k = 0; k < 128; ++k) {
          const float wc = rw1[(size_t)(192 + k) * 132 + t];
          const float wd = rw1[(size_t)(64 + k) * 132 + t];
          #pragma unroll
          for (int r = 0; r < 4; ++r) {
            cc[r] += sbuf[r][k] * wc;
            dd[r] += sbuf[r][k] * wd;
          }
        }
      }
      for (int r = 0; r < 4; ++r) {
        c1[(size_t)(blk * 4 + r) * 160 + t] = cc[r];
        d1[(size_t)(blk * 4 + r) * 160 + t] = dd[r];
      }
    }
  } else {                          // red0[b,j,d] = max_i R[b,i,j,d]
    const int blk = mb - 357;
    const int b = blk >> 7, j = blk & 127;
    const float* R = in.p[2];
    const int d = t & 63, g = t >> 6;
    float m = -3.4e38f;
    for (int v = 0; v < 32; ++v) {
      const int i = v * 4 + g;
      m = fmaxf(m, R[((size_t)(b * 128 + i) * 128 + j) * 64 + d]);
    }
    sbuf[g][d] = m;
    __syncthreads();
    if (t < 64)
      red0[(size_t)blk * 64 + t] =
          fmaxf(fmaxf(sbuf[0][t], sbuf[1][t]), fmaxf(sbuf[2][t], sbuf[3][t]));
  }
}

// ---------------------------------------------------------------------------
// main R-branch kernel: one block per (b,i). 256 thr = 4 waves, 2x2 wave tile.
// L1: K=64 (R only) with C-init = c1[b,i]+d1[b,j]; L2: 160x160; L3: 160x64.
// Also emits red1[b,i,d] = max_j R[b,i,j,d] (f32, from the staging pass).
// ---------------------------------------------------------------------------
__global__ __launch_bounds__(256, 2) void mainR_kernel(const float* __restrict__ R,
    const float* __restrict__ c1, const float* __restrict__ d1,
    const float* __restrict__ rb2, const float* __restrict__ rb3,
    const f16* __restrict__ wpk, float* __restrict__ red1, float* __restrict__ outR)
{
  __shared__ f16 Xr[128][72];
  __shared__ f16 Hs[128][168];
  __shared__ float redp[4][64];
  const int blk = blockIdx.x;                 // b*128 + i
  const int t = threadIdx.x, lane = t & 63, w = t >> 6;
  const int wm = w >> 1, wn = w & 1;
  const int rbase = wm * 64, nbase = wn * 80;
  const int lr = (lane >> 4) << 2;            // C-frag row group
  const int lc = lane & 15;                   // C-frag col / A-frag row
  const int lk = (lane >> 4) << 3;            // A/B-frag k offset

  const float* Rb = R + (size_t)blk * 8192;
  float mx0 = -3.4e38f, mx1 = -3.4e38f, mx2 = -3.4e38f, mx3 = -3.4e38f;
  #pragma unroll
  for (int v = 0; v < 8; ++v) {
    const int quad = v * 256 + t;
    const int j = quad >> 4, kq = quad & 15;
    f32x4 rv = *(const f32x4*)(Rb + (size_t)j * 64 + kq * 4);
    f16x4 hv;
    hv[0] = (f16)rv[0]; hv[1] = (f16)rv[1]; hv[2] = (f16)rv[2]; hv[3] = (f16)rv[3];
    *(f16x4*)(&Xr[j][kq * 4]) = hv;
    mx0 = fmaxf(mx0, rv[0]); mx1 = fmaxf(mx1, rv[1]);
    mx2 = fmaxf(mx2, rv[2]); mx3 = fmaxf(mx3, rv[3]);
  }
  #pragma unroll
  for (int s = 16; s < 64; s <<= 1) {
    mx0 = fmaxf(mx0, __shfl_xor(mx0, s));
    mx1 = fmaxf(mx1, __shfl_xor(mx1, s));
    mx2 = fmaxf(mx2, __shfl_xor(mx2, s));
    mx3 = fmaxf(mx3, __shfl_xor(mx3, s));
  }
  if (lane < 16) {
    redp[w][lane * 4 + 0] = mx0; redp[w][lane * 4 + 1] = mx1;
    redp[w][lane * 4 + 2] = mx2; redp[w][lane * 4 + 3] = mx3;
  }
  __syncthreads();
  if (t < 64)
    red1[(size_t)blk * 64 + t] =
        fmaxf(fmaxf(redp[0][t], redp[1][t]), fmaxf(redp[2][t], redp[3][t]));

  // ---- L1 ----
  const int b = blk >> 7;
  const float* c1r = c1 + (size_t)blk * 160;
  const float* d1b = d1 + (size_t)b * 128 * 160;
  f32x4 acc[4][5];
  #pragma unroll
  for (int mi2 = 0; mi2 < 4; ++mi2) {
    #pragma unroll
    for (int n5 = 0; n5 < 5; ++n5) {
      const int n = nbase + n5 * 16 + lc;
      const float cv = c1r[n];
      #pragma unroll
      for (int r = 0; r < 4; ++r) {
        const int j = rbase + mi2 * 16 + lr + r;
        acc[mi2][n5][r] = cv + d1b[(size_t)j * 160 + n];
      }
    }
  }
  const f16x8* W1p = (const f16x8*)(wpk + OFF_RW1A);
  #pragma unroll
  for (int kk = 0; kk < 2; ++kk) {
    f16x8 a[4];
    #pragma unroll
    for (int mi2 = 0; mi2 < 4; ++mi2)
      a[mi2] = *(const f16x8*)(&Xr[rbase + mi2 * 16 + lc][kk * 32 + lk]);
    #pragma unroll
    for (int n5 = 0; n5 < 5; ++n5) {
      const f16x8 bf = W1p[(size_t)(kk * 10 + wn * 5 + n5) * 64 + lane];
      #pragma unroll
      for (int mi2 = 0; mi2 < 4; ++mi2)
        acc[mi2][n5] = MFMA16(a[mi2], bf, acc[mi2][n5]);
    }
  }
  #pragma unroll
  for (int mi2 = 0; mi2 < 4; ++mi2)
    #pragma unroll
    for (int n5 = 0; n5 < 5; ++n5)
      #pragma unroll
      for (int r = 0; r < 4; ++r)
        Hs[rbase + mi2 * 16 + lr + r][nbase + n5 * 16 + lc] =
            (f16)fmaxf(acc[mi2][n5][r], 0.f);
  __syncthreads();

  // ---- L2 ----
  #pragma unroll
  for (int mi2 = 0; mi2 < 4; ++mi2)
    #pragma unroll
    for (int n5 = 0; n5 < 5; ++n5) {
      const int n = nbase + n5 * 16 + lc;
      const float bv = (n < 132) ? rb2[n] : 0.f;
      #pragma unroll
      for (int r = 0; r < 4; ++r) acc[mi2][n5][r] = bv;
    }
  const f16x8* W2p = (const f16x8*)(wpk + OFF_RW2);
  #pragma unroll
  for (int kk = 0; kk < 5; ++kk) {
    f16x8 a[4];
    #pragma unroll
    for (int mi2 = 0; mi2 < 4; ++mi2)
      a[mi2] = *(const f16x8*)(&Hs[rbase + mi2 * 16 + lc][kk * 32 + lk]);
    #pragma unroll
    for (int n5 = 0; n5 < 5; ++n5) {
      const f16x8 bf = W2p[(size_t)(kk * 10 + wn * 5 + n5) * 64 + lane];
      #pragma unroll
      for (int mi2 = 0; mi2 < 4; ++mi2)
        acc[mi2][n5] = MFMA16(a[mi2], bf, acc[mi2][n5]);
    }
  }
  __syncthreads();    // all H1 reads complete before overwrite
  #pragma unroll
  for (int mi2 = 0; mi2 < 4; ++mi2)
    #pragma unroll
    for (int n5 = 0; n5 < 5; ++n5)
      #pragma unroll
      for (int r = 0; r < 4; ++r)
        Hs[rbase + mi2 * 16 + lr + r][nbase + n5 * 16 + lc] =
            (f16)fmaxf(acc[mi2][n5][r], 0.f);
  __syncthreads();

  // ---- L3 ----
  f32x4 acc3[4][2];
  const int n3base = wn * 32;
  #pragma unroll
  for (int mi2 = 0; mi2 < 4; ++mi2)
    #pragma unroll
    for (int n2 = 0; n2 < 2; ++n2) {
      const float bv = rb3[n3base + n2 * 16 + lc];
      #pragma unroll
      for (int r = 0; r < 4; ++r) acc3[mi2][n2][r] = bv;
    }
  const f16x8* W3p = (const f16x8*)(wpk + OFF_RW3);
  #pragma unroll
  for (int kk = 0; kk < 5; ++kk) {
    f16x8 a[4];
    #pragma unroll
    for (int mi2 = 0; mi2 < 4; ++mi2)
      a[mi2] = *(const f16x8*)(&Hs[rbase + mi2 * 16 + lc][kk * 32 + lk]);
    #pragma unroll
    for (int n2 = 0; n2 < 2; ++n2) {
      const f16x8 bf = W3p[(size_t)(kk * 4 + wn * 2 + n2) * 64 + lane];
      #pragma unroll
      for (int mi2 = 0; mi2 < 4; ++mi2)
        acc3[mi2][n2] = MFMA16(a[mi2], bf, acc3[mi2][n2]);
    }
  }
  float* Ro = outR + (size_t)blk * 8192;
  #pragma unroll
  for (int mi2 = 0; mi2 < 4; ++mi2)
    #pragma unroll
    for (int n2 = 0; n2 < 2; ++n2)
      #pragma unroll
      for (int r = 0; r < 4; ++r) {
        const int j = rbase + mi2 * 16 + lr + r;
        const int n = n3base + n2 * 16 + lc;
        Ro[(size_t)j * 64 + n] = 1.f / (1.f + __expf(-5.f * acc3[mi2][n2][r]));
      }
}

// ---------------------------------------------------------------------------
// small kernel: blocks 0..15 = Q branch (64 rows each), block 16 = P branch.
// 128 thr = 2 waves, each wave owns 32 rows; K streamed in 4 chunks of 64.
// ---------------------------------------------------------------------------
__global__ __launch_bounds__(128) void small_kernel(const float* __restrict__ P,
    const float* __restrict__ Q,
    const float* __restrict__ qb2, const float* __restrict__ qb3,
    const float* __restrict__ pb1, const float* __restrict__ pb2, const float* __restrict__ pb3,
    const f16* __restrict__ wpk, const float* __restrict__ e1q, const float* __restrict__ qmax,
    const float* __restrict__ red0, const float* __restrict__ red1,
    float* __restrict__ outP, float* __restrict__ outQ)
{
  __shared__ f16 Xc[64][72];
  __shared__ f16 Hs2[64][168];
  const int blk = blockIdx.x;
  const bool isP = (blk == 16);
  const int t = threadIdx.x, lane = t & 63, w = t >> 6;
  const int lr = (lane >> 4) << 2, lc = lane & 15, lk = (lane >> 4) << 3;
  const int b = blk >> 1, x0 = (blk & 1) * 64;
  const f16x8* W1p = (const f16x8*)(wpk + (isP ? OFF_PW1 : OFF_QW1));
  const f16x8* W2p = (const f16x8*)(wpk + (isP ? OFF_PW2 : OFF_QW2));
  const f16x8* W3p = (const f16x8*)(wpk + (isP ? OFF_PW3 : OFF_QW3));

  f32x4 acc[2][10];
  #pragma unroll
  for (int mi2 = 0; mi2 < 2; ++mi2)
    #pragma unroll
    for (int nn = 0; nn < 10; ++nn) {
      const int n = nn * 16 + lc;
      const float cv = isP ? ((n < 132) ? pb1[n] : 0.f) : e1q[b * 160 + n];
      #pragma unroll
      for (int r = 0; r < 4; ++r) acc[mi2][nn][r] = cv;
    }

  for (int c = 0; c < 4; ++c) {
    __syncthreads();
    for (int o = t; o < 1024; o += 128) {
      const int rr = o >> 4, kq = o & 15;
      f32x4 v = {0.f, 0.f, 0.f, 0.f};
      if (isP) {
        if (rr < 8) {
          const float* s = (c < 2) ? (qmax + rr * 128 + c * 64) : (P + rr * 128 + (c - 2) * 64);
          v = *(const f32x4*)(s + kq * 4);
        }
      } else {
        const size_t rowg = (size_t)(b * 128 + x0 + rr);
        const float* s = (c < 2) ? (Q + rowg * 128 + c * 64)
                                 : (((c == 2) ? red0 : red1) + rowg * 64);
        v = *(const f32x4*)(s + kq * 4);
      }
      f16x4 hv;
      hv[0] = (f16)v[0]; hv[1] = (f16)v[1]; hv[2] = (f16)v[2]; hv[3] = (f16)v[3];
      *(f16x4*)(&Xc[rr][kq * 4]) = hv;
    }
    __syncthreads();
    #pragma unroll
    for (int kk = 0; kk < 2; ++kk) {
      f16x8 a[2];
      #pragma unroll
      for (int mi2 = 0; mi2 < 2; ++mi2)
        a[mi2] = *(const f16x8*)(&Xc[w * 32 + mi2 * 16 + lc][kk * 32 + lk]);
      const int kg = c * 2 + kk;
      #pragma unroll
      for (int nn = 0; nn < 10; ++nn) {
        const f16x8 bf = W1p[(size_t)(kg * 10 + nn) * 64 + lane];
        #pragma unroll
        for (int mi2 = 0; mi2 < 2; ++mi2)
          acc[mi2][nn] = MFMA16(a[mi2], bf, acc[mi2][nn]);
      }
    }
  }
  #pragma unroll
  for (int mi2 = 0; mi2 < 2; ++mi2)
    #pragma unroll
    for (int nn = 0; nn < 10; ++nn)
      #pragma unroll
      for (int r = 0; r < 4; ++r)
        Hs2[w * 32 + mi2 * 16 + lr + r][nn * 16 + lc] = (f16)fmaxf(acc[mi2][nn][r], 0.f);

  // L2 (intra-wave rows)
  #pragma unroll
  for (int mi2 = 0; mi2 < 2; ++mi2)
    #pragma unroll
    for (int nn = 0; nn < 10; ++nn) {
      const int n = nn * 16 + lc;
      const float bv = (n < 132) ? (isP ? pb2[n] : qb2[n]) : 0.f;
      #pragma unroll
      for (int r = 0; r < 4; ++r) acc[mi2][nn][r] = bv;
    }
  #pragma unroll
  for (int kk = 0; kk < 5; ++kk) {
    f16x8 a[2];
    #pragma unroll
    for (int mi2 = 0; mi2 < 2; ++mi2)
      a[mi2] = *(const f16x8*)(&Hs2[w * 32 + mi2 * 16 + lc][kk * 32 + lk]);
    #pragma unroll
    for (int nn = 0; nn < 10; ++nn) {
      const f16x8 bf = W2p[(size_t)(kk * 10 + nn) * 64 + lane];
      #pragma unroll
      for (int mi2 = 0; mi2 < 2; ++mi2)
        acc[mi2][nn] = MFMA16(a[mi2], bf, acc[mi2][nn]);
    }
  }
  #pragma unroll
  for (int mi2 = 0; mi2 < 2; ++mi2)
    #pragma unroll
    for (int nn = 0; nn < 10; ++nn)
      #pragma unroll
      for (int r = 0; r < 4; ++r)
        Hs2[w * 32 + mi2 * 16 + lr + r][nn * 16 + lc] = (f16)fmaxf(acc[mi2][nn][r], 0.f);

  // L3
  f32x4 acc3[2][4];
  #pragma unroll
  for (int mi2 = 0; mi2 < 2; ++mi2)
    #pragma unroll
    for (int n2 = 0; n2 < 4; ++n2) {
      const int n = n2 * 16 + lc;
      const float bv = isP ? pb3[n] : qb3[n];
      #pragma unroll
      for (int r = 0; r < 4; ++r) acc3[mi2][n2][r] = bv;
    }
  #pragma unroll
  for (int kk = 0; kk < 5; ++kk) {
    f16x8 a[2];
    #pragma unroll
    for (int mi2 = 0; mi2 < 2; ++mi2)
      a[mi2] = *(const f16x8*)(&Hs2[w * 32 + mi2 * 16 + lc][kk * 32 + lk]);
    #pragma unroll
    for (int n2 = 0; n2 < 4; ++n2) {
      const f16x8 bf = W3p[(size_t)(kk * 4 + n2) * 64 + lane];
      #pragma unroll
      for (int mi2 = 0; mi2 < 2; ++mi2)
        acc3[mi2][n2] = MFMA16(a[mi2], bf, acc3[mi2][n2]);
    }
  }
  #pragma unroll
  for (int mi2 = 0; mi2 < 2; ++mi2)
    #pragma unroll
    for (int n2 = 0; n2 < 4; ++n2)
      #pragma unroll
      for (int r = 0; r < 4; ++r) {
        const int rr = w * 32 + mi2 * 16 + lr + r;
        const int n = n2 * 16 + lc;
        const float s = 1.f / (1.f + __expf(-5.f * acc3[mi2][n2][r]));
        if (isP) {
          if (rr < 8) outP[rr * 64 + n] = s;
        } else {
          outQ[((size_t)(b * 128 + x0 + rr)) * 64 + n] = s;
        }
      }
}

extern "C" void kernel_launch(void* const* d_in, const int* in_sizes, int n_in,
                              void* d_out, int out_size, void* d_ws, size_t ws_size,
                              hipStream_t stream) {
  (void)in_sizes; (void)n_in; (void)out_size; (void)ws_size;
  InPtrs ip;
  for (int i = 0; i < 21; ++i) ip.p[i] = (const float*)d_in[i];

  char* ws = (char*)d_ws;
  f16* wpk = (f16*)ws;
  float* wsf = (float*)(ws + PACK_BYTES);
  float* c1 = wsf;
  float* d1 = wsf + 163840;
  float* e1q = wsf + 327680;
  float* qmax = wsf + 328960;
  float* red0 = wsf + 329984;
  float* red1 = wsf + 395520;

  float* outP = (float*)d_out;
  float* outQ = outP + 512;
  float* outR = outP + 66048;

  prep_kernel<<<dim3(1381), dim3(256), 0, stream>>>(ip, wpk, c1, d1, e1q, qmax, red0);
  mainR_kernel<<<dim3(1024), dim3(256), 0, stream>>>((const float*)d_in[2], c1, d1,
      (const float*)d_in[18], (const float*)d_in[20], wpk, red1, outR);
  small_kernel<<<dim3(17), dim3(128), 0, stream>>>((const float*)d_in[0], (const float*)d_in[1],
      (const float*)d_in[12], (const float*)d_in[14],
      (const float*)d_in[4], (const float*)d_in[6], (const float*)d_in[8],
      wpk, e1q, qmax, red0, red1, outP, outQ);
}

// Round 2
// 95.438 us; speedup vs baseline: 1.6857x; 1.6857x over previous
//
#include <hip/hip_runtime.h>

typedef _Float16 f16;
typedef f16 f16x8 __attribute__((ext_vector_type(8)));
typedef f16 f16x4 __attribute__((ext_vector_type(4)));
typedef float f32x4 __attribute__((ext_vector_type(4)));

#define MFMA16(a, b, c) __builtin_amdgcn_mfma_f32_16x16x32_f16(a, b, c, 0, 0, 0)

// packed-weight offsets in f16 elements within d_ws
#define OFF_RW1A 0
#define OFF_RW2  10240
#define OFF_RW3  35840
#define OFF_QW1  46080
#define OFF_QW2  87040
#define OFF_QW3  112640
#define OFF_PW1  122880
#define OFF_PW2  163840
#define OFF_PW3  189440
#define PACK_BYTES 399360   // 199680 f16

// prep grid layout: [0,1024) red0 | [1024,1123) pack | [1123,1131) qmax
//                   [1131,1139) e1q | [1139,1395) c1/d1
#define PREP_BLOCKS 1395

struct InPtrs { const float* p[21]; };

// pack-branch tables at file scope (function-local runtime-indexed arrays
// would be allocated in scratch — rule: static placement, cached loads)
__device__ const int g_mSrc[9] = {15, 17, 19, 9, 11, 13, 3, 5, 7};
__device__ const int g_mK0[9]  = {0, 0, 0, 128, 0, 0, 0, 0, 0};
__device__ const int g_mK[9]   = {64, 132, 132, 256, 132, 132, 256, 132, 132};
__device__ const int g_mN[9]   = {132, 132, 64, 132, 132, 64, 132, 132, 64};
__device__ const int g_mNT[9]  = {10, 10, 4, 10, 10, 4, 10, 10, 4};
__device__ const int g_mDst[9] = {OFF_RW1A, OFF_RW2, OFF_RW3, OFF_QW1, OFF_QW2, OFF_QW3,
                                  OFF_PW1, OFF_PW2, OFF_PW3};
__device__ const int g_mBlk0[9] = {1024, 1029, 1042, 1047, 1067, 1080, 1085, 1105, 1118};

__global__ __launch_bounds__(256) void prep_kernel(InPtrs in, f16* __restrict__ wpk,
    float* __restrict__ c1, float* __restrict__ d1, float* __restrict__ e1q,
    float* __restrict__ qmax, float* __restrict__ red0)
{
  __shared__ float sbuf[1024];
  const int mb = blockIdx.x, t = threadIdx.x;

  if (mb < 1024) {
    // red0[b,j,d] = max_i R[b,i,j,d]; one block per (b,j).
    // thread: d-quad d4 = t&15, i-group g = t>>4; 8 independent f32x4 loads.
    const int b = mb >> 7, j = mb & 127;
    const float* base = in.p[2] + (size_t)b * 128 * 8192 + (size_t)j * 64 + (t & 15) * 4;
    const int g = t >> 4;
    f32x4 mm[8];
    #pragma unroll
    for (int v = 0; v < 8; ++v)
      mm[v] = *(const f32x4*)(base + (size_t)(g + 16 * v) * 8192);
    #pragma unroll
    for (int s = 4; s > 0; s >>= 1)
      #pragma unroll
      for (int v = 0; v < 4; ++v)
        if (v < s) {
          mm[v][0] = fmaxf(mm[v][0], mm[v + s][0]);
          mm[v][1] = fmaxf(mm[v][1], mm[v + s][1]);
          mm[v][2] = fmaxf(mm[v][2], mm[v + s][2]);
          mm[v][3] = fmaxf(mm[v][3], mm[v + s][3]);
        }
    float* sr = sbuf + g * 64 + (t & 15) * 4;
    sr[0] = mm[0][0]; sr[1] = mm[0][1]; sr[2] = mm[0][2]; sr[3] = mm[0][3];
    __syncthreads();
    if (t < 64) {
      float m = sbuf[t];
      #pragma unroll
      for (int g2 = 1; g2 < 16; ++g2) m = fmaxf(m, sbuf[g2 * 64 + t]);
      red0[(size_t)mb * 64 + t] = m;
    }
  } else if (mb < 1123) {
    // weight pack into MFMA B-fragment layout
    int mi = 8;
    while (mi > 0 && mb < g_mBlk0[mi]) --mi;
    const int NT = g_mNT[mi], K = g_mK[mi], N = g_mN[mi], K0 = g_mK0[mi];
    const int L = (mb - g_mBlk0[mi]) * 256 + t;
    const int lanes = ((K + 31) >> 5) * NT * 64;
    if (L < lanes) {
      const int lane = L & 63, tile = L >> 6;
      const int kk = tile / NT, nn = tile % NT;
      const float* src = in.p[g_mSrc[mi]];
      const int n = nn * 16 + (lane & 15);
      const int kb = kk * 32 + ((lane >> 4) << 3);
      f16x8 v;
      #pragma unroll
      for (int u = 0; u < 8; ++u) {
        const int k = kb + u;
        float f = (k < K && n < N) ? src[(size_t)(K0 + k) * N + n] : 0.f;
        v[u] = (f16)f;
      }
      *(f16x8*)(wpk + g_mDst[mi] + (size_t)L * 8) = v;
    }
  } else if (mb < 1131) {
    // qmax[b,d] = max_i Q[b,i,d]; one block per b, 4 independent chains/thread
    const int b = mb - 1123;
    const float* Qb = in.p[1] + (size_t)b * 128 * 128;
    const int d = t & 127, g = t >> 7;           // g in {0,1}: i-half
    float m0 = -3.4e38f, m1 = m0, m2 = m0, m3 = m0;
    #pragma unroll
    for (int v = 0; v < 16; ++v) {
      const int i = g * 64 + v * 4;
      m0 = fmaxf(m0, Qb[(size_t)(i + 0) * 128 + d]);
      m1 = fmaxf(m1, Qb[(size_t)(i + 1) * 128 + d]);
      m2 = fmaxf(m2, Qb[(size_t)(i + 2) * 128 + d]);
      m3 = fmaxf(m3, Qb[(size_t)(i + 3) * 128 + d]);
    }
    sbuf[g * 128 + d] = fmaxf(fmaxf(m0, m1), fmaxf(m2, m3));
    __syncthreads();
    if (t < 128) qmax[b * 128 + t] = fmaxf(sbuf[t], sbuf[128 + t]);
  } else if (mb < 1139) {
    // e1q[b,n] = P[b] . q_w1[0:128] + q_b1; one block per b
    const int b = mb - 1131;
    const float* P = in.p[0]; const float* qw1 = in.p[9]; const float* qb1 = in.p[10];
    if (t < 160) {
      float a = 0.f;
      if (t < 132) {
        float a0 = 0.f, a1 = 0.f, a2 = 0.f, a3 = 0.f;
        for (int k = 0; k < 128; k += 4) {
          a0 += P[b * 128 + k + 0] * qw1[(size_t)(k + 0) * 132 + t];
          a1 += P[b * 128 + k + 1] * qw1[(size_t)(k + 1) * 132 + t];
          a2 += P[b * 128 + k + 2] * qw1[(size_t)(k + 2) * 132 + t];
          a3 += P[b * 128 + k + 3] * qw1[(size_t)(k + 3) * 132 + t];
        }
        a = qb1[t] + (a0 + a1) + (a2 + a3);
      }
      e1q[b * 160 + t] = a;
    }
  } else {
    // c1/d1 (r-branch folded Q contributions), 4 Q-rows per block
    const int blk = mb - 1139;
    const float* Q = in.p[1]; const float* rw1 = in.p[15]; const float* rb1 = in.p[16];
    for (int o = t; o < 512; o += 256) sbuf[o] = Q[(size_t)blk * 512 + o];
    __syncthreads();
    if (t < 160) {
      float cc[4], dd[4];
      #pragma unroll
      for (int r = 0; r < 4; ++r) { cc[r] = 0.f; dd[r] = 0.f; }
      if (t < 132) {
        const float bb = rb1[t];
        #pragma unroll
        for (int r = 0; r < 4; ++r) cc[r] = bb;
        for (int k = 0; k < 128; ++k) {
          const float wc = rw1[(size_t)(192 + k) * 132 + t];
          const float wd = rw1[(size_t)(64 + k) * 132 + t];
          #pragma unroll
          for (int r = 0; r < 4; ++r) {
            cc[r] += sbuf[r * 128 + k] * wc;
            dd[r] += sbuf[r * 128 + k] * wd;
          }
        }
      }
      for (int r = 0; r < 4; ++r) {
        c1[(size_t)(blk * 4 + r) * 160 + t] = cc[r];
        d1[(size_t)(blk * 4 + r) * 160 + t] = dd[r];
      }
    }
  }
}

// ---------------------------------------------------------------------------
// main R-branch kernel: one block per (b,i). 256 thr = 4 waves, 2x2 wave tile.
// L1: K=64 (R only) with C-init = c1[b,i]+d1[b,j]; L2: 160x160; L3: 160x64.
// Also emits red1[b,i,d] = max_j R[b,i,j,d] (f32, from the staging pass).
// ---------------------------------------------------------------------------
__global__ __launch_bounds__(256, 2) void mainR_kernel(const float* __restrict__ R,
    const float* __restrict__ c1, const float* __restrict__ d1,
    const float* __restrict__ rb2, const float* __restrict__ rb3,
    const f16* __restrict__ wpk, float* __restrict__ red1, float* __restrict__ outR)
{
  __shared__ f16 Xr[128][72];
  __shared__ f16 Hs[128][168];
  __shared__ float redp[4][64];
  const int blk = blockIdx.x;                 // b*128 + i
  const int t = threadIdx.x, lane = t & 63, w = t >> 6;
  const int wm = w >> 1, wn = w & 1;
  const int rbase = wm * 64, nbase = wn * 80;
  const int lr = (lane >> 4) << 2;            // C-frag row group
  const int lc = lane & 15;                   // C-frag col / A-frag row
  const int lk = (lane >> 4) << 3;            // A/B-frag k offset

  const float* Rb = R + (size_t)blk * 8192;
  float mx0 = -3.4e38f, mx1 = -3.4e38f, mx2 = -3.4e38f, mx3 = -3.4e38f;
  #pragma unroll
  for (int v = 0; v < 8; ++v) {
    const int quad = v * 256 + t;
    const int j = quad >> 4, kq = quad & 15;
    f32x4 rv = *(const f32x4*)(Rb + (size_t)j * 64 + kq * 4);
    f16x4 hv;
    hv[0] = (f16)rv[0]; hv[1] = (f16)rv[1]; hv[2] = (f16)rv[2]; hv[3] = (f16)rv[3];
    *(f16x4*)(&Xr[j][kq * 4]) = hv;
    mx0 = fmaxf(mx0, rv[0]); mx1 = fmaxf(mx1, rv[1]);
    mx2 = fmaxf(mx2, rv[2]); mx3 = fmaxf(mx3, rv[3]);
  }
  #pragma unroll
  for (int s = 16; s < 64; s <<= 1) {
    mx0 = fmaxf(mx0, __shfl_xor(mx0, s));
    mx1 = fmaxf(mx1, __shfl_xor(mx1, s));
    mx2 = fmaxf(mx2, __shfl_xor(mx2, s));
    mx3 = fmaxf(mx3, __shfl_xor(mx3, s));
  }
  if (lane < 16) {
    redp[w][lane * 4 + 0] = mx0; redp[w][lane * 4 + 1] = mx1;
    redp[w][lane * 4 + 2] = mx2; redp[w][lane * 4 + 3] = mx3;
  }
  __syncthreads();
  if (t < 64)
    red1[(size_t)blk * 64 + t] =
        fmaxf(fmaxf(redp[0][t], redp[1][t]), fmaxf(redp[2][t], redp[3][t]));

  // ---- L1 ----
  const int b = blk >> 7;
  const float* c1r = c1 + (size_t)blk * 160;
  const float* d1b = d1 + (size_t)b * 128 * 160;
  f32x4 acc[4][5];
  #pragma unroll
  for (int mi2 = 0; mi2 < 4; ++mi2) {
    #pragma unroll
    for (int n5 = 0; n5 < 5; ++n5) {
      const int n = nbase + n5 * 16 + lc;
      const float cv = c1r[n];
      #pragma unroll
      for (int r = 0; r < 4; ++r) {
        const int j = rbase + mi2 * 16 + lr + r;
        acc[mi2][n5][r] = cv + d1b[(size_t)j * 160 + n];
      }
    }
  }
  const f16x8* W1p = (const f16x8*)(wpk + OFF_RW1A);
  #pragma unroll
  for (int kk = 0; kk < 2; ++kk) {
    f16x8 a[4];
    #pragma unroll
    for (int mi2 = 0; mi2 < 4; ++mi2)
      a[mi2] = *(const f16x8*)(&Xr[rbase + mi2 * 16 + lc][kk * 32 + lk]);
    #pragma unroll
    for (int n5 = 0; n5 < 5; ++n5) {
      const f16x8 bf = W1p[(size_t)(kk * 10 + wn * 5 + n5) * 64 + lane];
      #pragma unroll
      for (int mi2 = 0; mi2 < 4; ++mi2)
        acc[mi2][n5] = MFMA16(a[mi2], bf, acc[mi2][n5]);
    }
  }
  #pragma unroll
  for (int mi2 = 0; mi2 < 4; ++mi2)
    #pragma unroll
    for (int n5 = 0; n5 < 5; ++n5)
      #pragma unroll
      for (int r = 0; r < 4; ++r)
        Hs[rbase + mi2 * 16 + lr + r][nbase + n5 * 16 + lc] =
            (f16)fmaxf(acc[mi2][n5][r], 0.f);
  __syncthreads();

  // ---- L2 ----
  #pragma unroll
  for (int mi2 = 0; mi2 < 4; ++mi2)
    #pragma unroll
    for (int n5 = 0; n5 < 5; ++n5) {
      const int n = nbase + n5 * 16 + lc;
      const float bv = (n < 132) ? rb2[n] : 0.f;
      #pragma unroll
      for (int r = 0; r < 4; ++r) acc[mi2][n5][r] = bv;
    }
  const f16x8* W2p = (const f16x8*)(wpk + OFF_RW2);
  #pragma unroll
  for (int kk = 0; kk < 5; ++kk) {
    f16x8 a[4];
    #pragma unroll
    for (int mi2 = 0; mi2 < 4; ++mi2)
      a[mi2] = *(const f16x8*)(&Hs[rbase + mi2 * 16 + lc][kk * 32 + lk]);
    #pragma unroll
    for (int n5 = 0; n5 < 5; ++n5) {
      const f16x8 bf = W2p[(size_t)(kk * 10 + wn * 5 + n5) * 64 + lane];
      #pragma unroll
      for (int mi2 = 0; mi2 < 4; ++mi2)
        acc[mi2][n5] = MFMA16(a[mi2], bf, acc[mi2][n5]);
    }
  }
  __syncthreads();    // all H1 reads complete before overwrite
  #pragma unroll
  for (int mi2 = 0; mi2 < 4; ++mi2)
    #pragma unroll
    for (int n5 = 0; n5 < 5; ++n5)
      #pragma unroll
      for (int r = 0; r < 4; ++r)
        Hs[rbase + mi2 * 16 + lr + r][nbase + n5 * 16 + lc] =
            (f16)fmaxf(acc[mi2][n5][r], 0.f);
  __syncthreads();

  // ---- L3 ----
  f32x4 acc3[4][2];
  const int n3base = wn * 32;
  #pragma unroll
  for (int mi2 = 0; mi2 < 4; ++mi2)
    #pragma unroll
    for (int n2 = 0; n2 < 2; ++n2) {
      const float bv = rb3[n3base + n2 * 16 + lc];
      #pragma unroll
      for (int r = 0; r < 4; ++r) acc3[mi2][n2][r] = bv;
    }
  const f16x8* W3p = (const f16x8*)(wpk + OFF_RW3);
  #pragma unroll
  for (int kk = 0; kk < 5; ++kk) {
    f16x8 a[4];
    #pragma unroll
    for (int mi2 = 0; mi2 < 4; ++mi2)
      a[mi2] = *(const f16x8*)(&Hs[rbase + mi2 * 16 + lc][kk * 32 + lk]);
    #pragma unroll
    for (int n2 = 0; n2 < 2; ++n2) {
      const f16x8 bf = W3p[(size_t)(kk * 4 + wn * 2 + n2) * 64 + lane];
      #pragma unroll
      for (int mi2 = 0; mi2 < 4; ++mi2)
        acc3[mi2][n2] = MFMA16(a[mi2], bf, acc3[mi2][n2]);
    }
  }
  float* Ro = outR + (size_t)blk * 8192;
  #pragma unroll
  for (int mi2 = 0; mi2 < 4; ++mi2)
    #pragma unroll
    for (int n2 = 0; n2 < 2; ++n2)
      #pragma unroll
      for (int r = 0; r < 4; ++r) {
        const int j = rbase + mi2 * 16 + lr + r;
        const int n = n3base + n2 * 16 + lc;
        Ro[(size_t)j * 64 + n] = 1.f / (1.f + __expf(-5.f * acc3[mi2][n2][r]));
      }
}

// ---------------------------------------------------------------------------
// small kernel: blocks 0..15 = Q branch (64 rows each), block 16 = P branch.
// ---------------------------------------------------------------------------
__global__ __launch_bounds__(128) void small_kernel(const float* __restrict__ P,
    const float* __restrict__ Q,
    const float* __restrict__ qb2, const float* __restrict__ qb3,
    const float* __restrict__ pb1, const float* __restrict__ pb2, const float* __restrict__ pb3,
    const f16* __restrict__ wpk, const float* __restrict__ e1q, const float* __restrict__ qmax,
    const float* __restrict__ red0, const float* __restrict__ red1,
    float* __restrict__ outP, float* __restrict__ outQ)
{
  __shared__ f16 Xc[64][72];
  __shared__ f16 Hs2[64][168];
  const int blk = blockIdx.x;
  const bool isP = (blk == 16);
  const int t = threadIdx.x, lane = t & 63, w = t >> 6;
  const int lr = (lane >> 4) << 2, lc = lane & 15, lk = (lane >> 4) << 3;
  const int b = blk >> 1, x0 = (blk & 1) * 64;
  const f16x8* W1p = (const f16x8*)(wpk + (isP ? OFF_PW1 : OFF_QW1));
  const f16x8* W2p = (const f16x8*)(wpk + (isP ? OFF_PW2 : OFF_QW2));
  const f16x8* W3p = (const f16x8*)(wpk + (isP ? OFF_PW3 : OFF_QW3));

  f32x4 acc[2][10];
  #pragma unroll
  for (int mi2 = 0; mi2 < 2; ++mi2)
    #pragma unroll
    for (int nn = 0; nn < 10; ++nn) {
      const int n = nn * 16 + lc;
      const float cv = isP ? ((n < 132) ? pb1[n] : 0.f) : e1q[b * 160 + n];
      #pragma unroll
      for (int r = 0; r < 4; ++r) acc[mi2][nn][r] = cv;
    }

  for (int c = 0; c < 4; ++c) {
    __syncthreads();
    for (int o = t; o < 1024; o += 128) {
      const int rr = o >> 4, kq = o & 15;
      f32x4 v = {0.f, 0.f, 0.f, 0.f};
      if (isP) {
        if (rr < 8) {
          const float* s = (c < 2) ? (qmax + rr * 128 + c * 64) : (P + rr * 128 + (c - 2) * 64);
          v = *(const f32x4*)(s + kq * 4);
        }
      } else {
        const size_t rowg = (size_t)(b * 128 + x0 + rr);
        const float* s = (c < 2) ? (Q + rowg * 128 + c * 64)
                                 : (((c == 2) ? red0 : red1) + rowg * 64);
        v = *(const f32x4*)(s + kq * 4);
      }
      f16x4 hv;
      hv[0] = (f16)v[0]; hv[1] = (f16)v[1]; hv[2] = (f16)v[2]; hv[3] = (f16)v[3];
      *(f16x4*)(&Xc[rr][kq * 4]) = hv;
    }
    __syncthreads();
    #pragma unroll
    for (int kk = 0; kk < 2; ++kk) {
      f16x8 a[2];
      #pragma unroll
      for (int mi2 = 0; mi2 < 2; ++mi2)
        a[mi2] = *(const f16x8*)(&Xc[w * 32 + mi2 * 16 + lc][kk * 32 + lk]);
      const int kg = c * 2 + kk;
      #pragma unroll
      for (int nn = 0; nn < 10; ++nn) {
        const f16x8 bf = W1p[(size_t)(kg * 10 + nn) * 64 + lane];
        #pragma unroll
        for (int mi2 = 0; mi2 < 2; ++mi2)
          acc[mi2][nn] = MFMA16(a[mi2], bf, acc[mi2][nn]);
      }
    }
  }
  #pragma unroll
  for (int mi2 = 0; mi2 < 2; ++mi2)
    #pragma unroll
    for (int nn = 0; nn < 10; ++nn)
      #pragma unroll
      for (int r = 0; r < 4; ++r)
        Hs2[w * 32 + mi2 * 16 + lr + r][nn * 16 + lc] = (f16)fmaxf(acc[mi2][nn][r], 0.f);

  // L2
  #pragma unroll
  for (int mi2 = 0; mi2 < 2; ++mi2)
    #pragma unroll
    for (int nn = 0; nn < 10; ++nn) {
      const int n = nn * 16 + lc;
      const float bv = (n < 132) ? (isP ? pb2[n] : qb2[n]) : 0.f;
      #pragma unroll
      for (int r = 0; r < 4; ++r) acc[mi2][nn][r] = bv;
    }
  __syncthreads();
  #pragma unroll
  for (int kk = 0; kk < 5; ++kk) {
    f16x8 a[2];
    #pragma unroll
    for (int mi2 = 0; mi2 < 2; ++mi2)
      a[mi2] = *(const f16x8*)(&Hs2[w * 32 + mi2 * 16 + lc][kk * 32 + lk]);
    #pragma unroll
    for (int nn = 0; nn < 10; ++nn) {
      const f16x8 bf = W2p[(size_t)(kk * 10 + nn) * 64 + lane];
      #pragma unroll
      for (int mi2 = 0; mi2 < 2; ++mi2)
        acc[mi2][nn] = MFMA16(a[mi2], bf, acc[mi2][nn]);
    }
  }
  __syncthreads();
  #pragma unroll
  for (int mi2 = 0; mi2 < 2; ++mi2)
    #pragma unroll
    for (int nn = 0; nn < 10; ++nn)
      #pragma unroll
      for (int r = 0; r < 4; ++r)
        Hs2[w * 32 + mi2 * 16 + lr + r][nn * 16 + lc] = (f16)fmaxf(acc[mi2][nn][r], 0.f);

  // L3
  f32x4 acc3[2][4];
  #pragma unroll
  for (int mi2 = 0; mi2 < 2; ++mi2)
    #pragma unroll
    for (int n2 = 0; n2 < 4; ++n2) {
      const int n = n2 * 16 + lc;
      const float bv = isP ? pb3[n] : qb3[n];
      #pragma unroll
      for (int r = 0; r < 4; ++r) acc3[mi2][n2][r] = bv;
    }
  __syncthreads();
  #pragma unroll
  for (int kk = 0; kk < 5; ++kk) {
    f16x8 a[2];
    #pragma unroll
    for (int mi2 = 0; mi2 < 2; ++mi2)
      a[mi2] = *(const f16x8*)(&Hs2[w * 32 + mi2 * 16 + lc][kk * 32 + lk]);
    #pragma unroll
    for (int n2 = 0; n2 < 4; ++n2) {
      const f16x8 bf = W3p[(size_t)(kk * 4 + n2) * 64 + lane];
      #pragma unroll
      for (int mi2 = 0; mi2 < 2; ++mi2)
        acc3[mi2][n2] = MFMA16(a[mi2], bf, acc3[mi2][n2]);
    }
  }
  #pragma unroll
  for (int mi2 = 0; mi2 < 2; ++mi2)
    #pragma unroll
    for (int n2 = 0; n2 < 4; ++n2)
      #pragma unroll
      for (int r = 0; r < 4; ++r) {
        const int rr = w * 32 + mi2 * 16 + lr + r;
        const int n = n2 * 16 + lc;
        const float s = 1.f / (1.f + __expf(-5.f * acc3[mi2][n2][r]));
        if (isP) {
          if (rr < 8) outP[rr * 64 + n] = s;
        } else {
          outQ[((size_t)(b * 128 + x0 + rr)) * 64 + n] = s;
        }
      }
}

extern "C" void kernel_launch(void* const* d_in, const int* in_sizes, int n_in,
                              void* d_out, int out_size, void* d_ws, size_t ws_size,
                              hipStream_t stream) {
  (void)in_sizes; (void)n_in; (void)out_size; (void)ws_size;
  InPtrs ip;
  for (int i = 0; i < 21; ++i) ip.p[i] = (const float*)d_in[i];

  char* ws = (char*)d_ws;
  f16* wpk = (f16*)ws;
  float* wsf = (float*)(ws + PACK_BYTES);
  float* c1 = wsf;
  float* d1 = wsf + 163840;
  float* e1q = wsf + 327680;
  float* qmax = wsf + 328960;
  float* red0 = wsf + 329984;
  float* red1 = wsf + 395520;

  float* outP = (float*)d_out;
  float* outQ = outP + 512;
  float* outR = outP + 66048;

  prep_kernel<<<dim3(PREP_BLOCKS), dim3(256), 0, stream>>>(ip, wpk, c1, d1, e1q, qmax, red0);
  mainR_kernel<<<dim3(1024), dim3(256), 0, stream>>>((const float*)d_in[2], c1, d1,
      (const float*)d_in[18], (const float*)d_in[20], wpk, red1, outR);
  small_kernel<<<dim3(17), dim3(128), 0, stream>>>((const float*)d_in[0], (const float*)d_in[1],
      (const float*)d_in[12], (const float*)d_in[14],
      (const float*)d_in[4], (const float*)d_in[6], (const float*)d_in[8],
      wpk, e1q, qmax, red0, red1, outP, outQ);
}

// Round 3
// 73.631 us; speedup vs baseline: 2.1849x; 1.2962x over previous
//
#include <hip/hip_runtime.h>

typedef _Float16 f16;
typedef f16 f16x8 __attribute__((ext_vector_type(8)));
typedef f16 f16x4 __attribute__((ext_vector_type(4)));
typedef float f32x4 __attribute__((ext_vector_type(4)));

#define MFMA16(a, b, c) __builtin_amdgcn_mfma_f32_16x16x32_f16(a, b, c, 0, 0, 0)

// packed-weight offsets in f16 elements within d_ws
#define OFF_RW1A 0
#define OFF_RW2  10240
#define OFF_RW3  35840
#define OFF_QW1  46080
#define OFF_QW2  87040
#define OFF_QW3  112640
#define OFF_PW1  122880
#define OFF_PW2  163840
#define OFF_PW3  189440
#define PACK_BYTES 399360   // 199680 f16

// prep grid: [0,1024) red0 | [1024,1123) pack | [1123,1131) qmax
//            [1131,1139) e1q | [1139,1395) c1/d1 | [1395,2419) red1
#define PREP_BLOCKS 2419

struct InPtrs { const float* p[21]; };

__device__ const int g_mSrc[9] = {15, 17, 19, 9, 11, 13, 3, 5, 7};
__device__ const int g_mK0[9]  = {0, 0, 0, 128, 0, 0, 0, 0, 0};
__device__ const int g_mK[9]   = {64, 132, 132, 256, 132, 132, 256, 132, 132};
__device__ const int g_mN[9]   = {132, 132, 64, 132, 132, 64, 132, 132, 64};
__device__ const int g_mNT[9]  = {10, 10, 4, 10, 10, 4, 10, 10, 4};
__device__ const int g_mDst[9] = {OFF_RW1A, OFF_RW2, OFF_RW3, OFF_QW1, OFF_QW2, OFF_QW3,
                                  OFF_PW1, OFF_PW2, OFF_PW3};
__device__ const int g_mBlk0[9] = {1024, 1029, 1042, 1047, 1067, 1080, 1085, 1105, 1118};

__global__ __launch_bounds__(256) void prep_kernel(InPtrs in, f16* __restrict__ wpk,
    float* __restrict__ c1, float* __restrict__ d1, float* __restrict__ e1q,
    float* __restrict__ qmax, float* __restrict__ red0, float* __restrict__ red1)
{
  __shared__ float sbuf[1024];
  const int mb = blockIdx.x, t = threadIdx.x;

  if (mb < 1024) {
    // red0[b,j,d] = max_i R[b,i,j,d]; one block per (b,j); strided i.
    const int b = mb >> 7, j = mb & 127;
    const float* base = in.p[2] + (size_t)b * 128 * 8192 + (size_t)j * 64 + (t & 15) * 4;
    const int g = t >> 4;
    f32x4 mm[8];
    #pragma unroll
    for (int v = 0; v < 8; ++v)
      mm[v] = *(const f32x4*)(base + (size_t)(g + 16 * v) * 8192);
    #pragma unroll
    for (int s = 4; s > 0; s >>= 1)
      #pragma unroll
      for (int v = 0; v < 4; ++v)
        if (v < s) {
          mm[v][0] = fmaxf(mm[v][0], mm[v + s][0]);
          mm[v][1] = fmaxf(mm[v][1], mm[v + s][1]);
          mm[v][2] = fmaxf(mm[v][2], mm[v + s][2]);
          mm[v][3] = fmaxf(mm[v][3], mm[v + s][3]);
        }
    float* sr = sbuf + g * 64 + (t & 15) * 4;
    sr[0] = mm[0][0]; sr[1] = mm[0][1]; sr[2] = mm[0][2]; sr[3] = mm[0][3];
    __syncthreads();
    if (t < 64) {
      float m = sbuf[t];
      #pragma unroll
      for (int g2 = 1; g2 < 16; ++g2) m = fmaxf(m, sbuf[g2 * 64 + t]);
      red0[(size_t)mb * 64 + t] = m;
    }
  } else if (mb < 1123) {
    // weight pack into MFMA B-fragment layout
    int mi = 8;
    while (mi > 0 && mb < g_mBlk0[mi]) --mi;
    const int NT = g_mNT[mi], K = g_mK[mi], N = g_mN[mi], K0 = g_mK0[mi];
    const int L = (mb - g_mBlk0[mi]) * 256 + t;
    const int lanes = ((K + 31) >> 5) * NT * 64;
    if (L < lanes) {
      const int lane = L & 63, tile = L >> 6;
      const int kk = tile / NT, nn = tile % NT;
      const float* src = in.p[g_mSrc[mi]];
      const int n = nn * 16 + (lane & 15);
      const int kb = kk * 32 + ((lane >> 4) << 3);
      f16x8 v;
      #pragma unroll
      for (int u = 0; u < 8; ++u) {
        const int k = kb + u;
        float f = (k < K && n < N) ? src[(size_t)(K0 + k) * N + n] : 0.f;
        v[u] = (f16)f;
      }
      *(f16x8*)(wpk + g_mDst[mi] + (size_t)L * 8) = v;
    }
  } else if (mb < 1131) {
    // qmax[b,d] = max_i Q[b,i,d]
    const int b = mb - 1123;
    const float* Qb = in.p[1] + (size_t)b * 128 * 128;
    const int d = t & 127, g = t >> 7;
    float m0 = -3.4e38f, m1 = m0, m2 = m0, m3 = m0;
    #pragma unroll
    for (int v = 0; v < 16; ++v) {
      const int i = g * 64 + v * 4;
      m0 = fmaxf(m0, Qb[(size_t)(i + 0) * 128 + d]);
      m1 = fmaxf(m1, Qb[(size_t)(i + 1) * 128 + d]);
      m2 = fmaxf(m2, Qb[(size_t)(i + 2) * 128 + d]);
      m3 = fmaxf(m3, Qb[(size_t)(i + 3) * 128 + d]);
    }
    sbuf[g * 128 + d] = fmaxf(fmaxf(m0, m1), fmaxf(m2, m3));
    __syncthreads();
    if (t < 128) qmax[b * 128 + t] = fmaxf(sbuf[t], sbuf[128 + t]);
  } else if (mb < 1139) {
    // e1q[b,n] = P[b] . q_w1[0:128] + q_b1
    const int b = mb - 1131;
    const float* P = in.p[0]; const float* qw1 = in.p[9]; const float* qb1 = in.p[10];
    if (t < 160) {
      float a = 0.f;
      if (t < 132) {
        float a0 = 0.f, a1 = 0.f, a2 = 0.f, a3 = 0.f;
        for (int k = 0; k < 128; k += 4) {
          a0 += P[b * 128 + k + 0] * qw1[(size_t)(k + 0) * 132 + t];
          a1 += P[b * 128 + k + 1] * qw1[(size_t)(k + 1) * 132 + t];
          a2 += P[b * 128 + k + 2] * qw1[(size_t)(k + 2) * 132 + t];
          a3 += P[b * 128 + k + 3] * qw1[(size_t)(k + 3) * 132 + t];
        }
        a = qb1[t] + (a0 + a1) + (a2 + a3);
      }
      e1q[b * 160 + t] = a;
    }
  } else if (mb < 1395) {
    // c1/d1 (r-branch folded Q contributions), 4 Q-rows per block
    const int blk = mb - 1139;
    const float* Q = in.p[1]; const float* rw1 = in.p[15]; const float* rb1 = in.p[16];
    for (int o = t; o < 512; o += 256) sbuf[o] = Q[(size_t)blk * 512 + o];
    __syncthreads();
    if (t < 160) {
      float cc[4], dd[4];
      #pragma unroll
      for (int r = 0; r < 4; ++r) { cc[r] = 0.f; dd[r] = 0.f; }
      if (t < 132) {
        const float bb = rb1[t];
        #pragma unroll
        for (int r = 0; r < 4; ++r) cc[r] = bb;
        for (int k = 0; k < 128; ++k) {
          const float wc = rw1[(size_t)(192 + k) * 132 + t];
          const float wd = rw1[(size_t)(64 + k) * 132 + t];
          #pragma unroll
          for (int r = 0; r < 4; ++r) {
            cc[r] += sbuf[r * 128 + k] * wc;
            dd[r] += sbuf[r * 128 + k] * wd;
          }
        }
      }
      for (int r = 0; r < 4; ++r) {
        c1[(size_t)(blk * 4 + r) * 160 + t] = cc[r];
        d1[(size_t)(blk * 4 + r) * 160 + t] = dd[r];
      }
    }
  } else {
    // red1[b,i,d] = max_j R[b,i,j,d]; one block per (b,i); contiguous j.
    const int blk = mb - 1395;
    const float* base = in.p[2] + (size_t)blk * 8192 + (t & 15) * 4;
    const int g = t >> 4;
    f32x4 mm[8];
    #pragma unroll
    for (int v = 0; v < 8; ++v)
      mm[v] = *(const f32x4*)(base + (size_t)(g + 16 * v) * 64);
    #pragma unroll
    for (int s = 4; s > 0; s >>= 1)
      #pragma unroll
      for (int v = 0; v < 4; ++v)
        if (v < s) {
          mm[v][0] = fmaxf(mm[v][0], mm[v + s][0]);
          mm[v][1] = fmaxf(mm[v][1], mm[v + s][1]);
          mm[v][2] = fmaxf(mm[v][2], mm[v + s][2]);
          mm[v][3] = fmaxf(mm[v][3], mm[v + s][3]);
        }
    float* sr = sbuf + g * 64 + (t & 15) * 4;
    sr[0] = mm[0][0]; sr[1] = mm[0][1]; sr[2] = mm[0][2]; sr[3] = mm[0][3];
    __syncthreads();
    if (t < 64) {
      float m = sbuf[t];
      #pragma unroll
      for (int g2 = 1; g2 < 16; ++g2) m = fmaxf(m, sbuf[g2 * 64 + t]);
      red1[(size_t)blk * 64 + t] = m;
    }
  }
}

// ---------------------------------------------------------------------------
// main R-branch kernel: one block per (b,i). 256 thr = 4 waves, 2x2 wave tile.
// ---------------------------------------------------------------------------
__global__ __launch_bounds__(256, 2) void mainR_kernel(const float* __restrict__ R,
    const float* __restrict__ c1, const float* __restrict__ d1,
    const float* __restrict__ rb2, const float* __restrict__ rb3,
    const f16* __restrict__ wpk, float* __restrict__ outR)
{
  __shared__ f16 Xr[128][72];
  __shared__ f16 Hs[128][168];
  const int blk = blockIdx.x;                 // b*128 + i
  const int t = threadIdx.x, lane = t & 63, w = t >> 6;
  const int wm = w >> 1, wn = w & 1;
  const int rbase = wm * 64, nbase = wn * 80;
  const int lr = (lane >> 4) << 2;
  const int lc = lane & 15;
  const int lk = (lane >> 4) << 3;

  const float* Rb = R + (size_t)blk * 8192;
  #pragma unroll
  for (int v = 0; v < 8; ++v) {
    const int quad = v * 256 + t;
    const int j = quad >> 4, kq = quad & 15;
    f32x4 rv = *(const f32x4*)(Rb + (size_t)j * 64 + kq * 4);
    f16x4 hv;
    hv[0] = (f16)rv[0]; hv[1] = (f16)rv[1]; hv[2] = (f16)rv[2]; hv[3] = (f16)rv[3];
    *(f16x4*)(&Xr[j][kq * 4]) = hv;
  }

  // ---- L1 ----
  const int b = blk >> 7;
  const float* c1r = c1 + (size_t)blk * 160;
  const float* d1b = d1 + (size_t)b * 128 * 160;
  f32x4 acc[4][5];
  #pragma unroll
  for (int mi2 = 0; mi2 < 4; ++mi2) {
    #pragma unroll
    for (int n5 = 0; n5 < 5; ++n5) {
      const int n = nbase + n5 * 16 + lc;
      const float cv = c1r[n];
      #pragma unroll
      for (int r = 0; r < 4; ++r) {
        const int j = rbase + mi2 * 16 + lr + r;
        acc[mi2][n5][r] = cv + d1b[(size_t)j * 160 + n];
      }
    }
  }
  __syncthreads();
  const f16x8* W1p = (const f16x8*)(wpk + OFF_RW1A);
  #pragma unroll
  for (int kk = 0; kk < 2; ++kk) {
    f16x8 a[4];
    #pragma unroll
    for (int mi2 = 0; mi2 < 4; ++mi2)
      a[mi2] = *(const f16x8*)(&Xr[rbase + mi2 * 16 + lc][kk * 32 + lk]);
    #pragma unroll
    for (int n5 = 0; n5 < 5; ++n5) {
      const f16x8 bf = W1p[(size_t)(kk * 10 + wn * 5 + n5) * 64 + lane];
      #pragma unroll
      for (int mi2 = 0; mi2 < 4; ++mi2)
        acc[mi2][n5] = MFMA16(a[mi2], bf, acc[mi2][n5]);
    }
  }
  #pragma unroll
  for (int mi2 = 0; mi2 < 4; ++mi2)
    #pragma unroll
    for (int n5 = 0; n5 < 5; ++n5)
      #pragma unroll
      for (int r = 0; r < 4; ++r)
        Hs[rbase + mi2 * 16 + lr + r][nbase + n5 * 16 + lc] =
            (f16)fmaxf(acc[mi2][n5][r], 0.f);
  __syncthreads();

  // ---- L2 ----
  #pragma unroll
  for (int mi2 = 0; mi2 < 4; ++mi2)
    #pragma unroll
    for (int n5 = 0; n5 < 5; ++n5) {
      const int n = nbase + n5 * 16 + lc;
      const float bv = (n < 132) ? rb2[n] : 0.f;
      #pragma unroll
      for (int r = 0; r < 4; ++r) acc[mi2][n5][r] = bv;
    }
  const f16x8* W2p = (const f16x8*)(wpk + OFF_RW2);
  #pragma unroll
  for (int kk = 0; kk < 5; ++kk) {
    f16x8 a[4];
    #pragma unroll
    for (int mi2 = 0; mi2 < 4; ++mi2)
      a[mi2] = *(const f16x8*)(&Hs[rbase + mi2 * 16 + lc][kk * 32 + lk]);
    #pragma unroll
    for (int n5 = 0; n5 < 5; ++n5) {
      const f16x8 bf = W2p[(size_t)(kk * 10 + wn * 5 + n5) * 64 + lane];
      #pragma unroll
      for (int mi2 = 0; mi2 < 4; ++mi2)
        acc[mi2][n5] = MFMA16(a[mi2], bf, acc[mi2][n5]);
    }
  }
  __syncthreads();
  #pragma unroll
  for (int mi2 = 0; mi2 < 4; ++mi2)
    #pragma unroll
    for (int n5 = 0; n5 < 5; ++n5)
      #pragma unroll
      for (int r = 0; r < 4; ++r)
        Hs[rbase + mi2 * 16 + lr + r][nbase + n5 * 16 + lc] =
            (f16)fmaxf(acc[mi2][n5][r], 0.f);
  __syncthreads();

  // ---- L3 ----
  f32x4 acc3[4][2];
  const int n3base = wn * 32;
  #pragma unroll
  for (int mi2 = 0; mi2 < 4; ++mi2)
    #pragma unroll
    for (int n2 = 0; n2 < 2; ++n2) {
      const float bv = rb3[n3base + n2 * 16 + lc];
      #pragma unroll
      for (int r = 0; r < 4; ++r) acc3[mi2][n2][r] = bv;
    }
  const f16x8* W3p = (const f16x8*)(wpk + OFF_RW3);
  #pragma unroll
  for (int kk = 0; kk < 5; ++kk) {
    f16x8 a[4];
    #pragma unroll
    for (int mi2 = 0; mi2 < 4; ++mi2)
      a[mi2] = *(const f16x8*)(&Hs[rbase + mi2 * 16 + lc][kk * 32 + lk]);
    #pragma unroll
    for (int n2 = 0; n2 < 2; ++n2) {
      const f16x8 bf = W3p[(size_t)(kk * 4 + wn * 2 + n2) * 64 + lane];
      #pragma unroll
      for (int mi2 = 0; mi2 < 4; ++mi2)
        acc3[mi2][n2] = MFMA16(a[mi2], bf, acc3[mi2][n2]);
    }
  }
  float* Ro = outR + (size_t)blk * 8192;
  #pragma unroll
  for (int mi2 = 0; mi2 < 4; ++mi2)
    #pragma unroll
    for (int n2 = 0; n2 < 2; ++n2)
      #pragma unroll
      for (int r = 0; r < 4; ++r) {
        const int j = rbase + mi2 * 16 + lr + r;
        const int n = n3base + n2 * 16 + lc;
        Ro[(size_t)j * 64 + n] = 1.f / (1.f + __expf(-5.f * acc3[mi2][n2][r]));
      }
}

// ---------------------------------------------------------------------------
// small kernel: blocks 0..15 = Q branch (64 rows), block 16 = P branch.
// 256 thr = 4 waves (2 row-halves x 2 col-halves); weights staged in LDS.
// ---------------------------------------------------------------------------
__global__ __launch_bounds__(256) void small_kernel(const float* __restrict__ P,
    const float* __restrict__ Q,
    const float* __restrict__ qb2, const float* __restrict__ qb3,
    const float* __restrict__ pb1, const float* __restrict__ pb2, const float* __restrict__ pb3,
    const f16* __restrict__ wpk, const float* __restrict__ e1q, const float* __restrict__ qmax,
    const float* __restrict__ red0, const float* __restrict__ red1,
    float* __restrict__ outP, float* __restrict__ outQ)
{
  __shared__ f16 Xc[64][72];        //  9.2 KB
  __shared__ f16 Hs2[64][168];      // 21.5 KB
  __shared__ f16 Wb[40960];         // 80.0 KB weight stage
  const int blk = blockIdx.x;
  const bool isP = (blk == 16);
  const int t = threadIdx.x, lane = t & 63, w = t >> 6;
  const int wm = w >> 1, wn = w & 1;
  const int rb = wm * 32;
  const int lr = (lane >> 4) << 2, lc = lane & 15, lk = (lane >> 4) << 3;
  const int b = blk >> 1, x0 = (blk & 1) * 64;
  const f16* W1g = wpk + (isP ? OFF_PW1 : OFF_QW1);
  const f16* W2g = wpk + (isP ? OFF_PW2 : OFF_QW2);
  const f16* W3g = wpk + (isP ? OFF_PW3 : OFF_QW3);

  // stage L1 weights: 80 frags x 1 KB (no acc live -> deep load pipelining)
  for (int f = w; f < 80; f += 4)
    *(f16x8*)(&Wb[f * 512 + lane * 8]) = *(const f16x8*)(W1g + (size_t)f * 512 + lane * 8);

  f32x4 acc[2][5];
  #pragma unroll
  for (int mi2 = 0; mi2 < 2; ++mi2)
    #pragma unroll
    for (int n5 = 0; n5 < 5; ++n5) {
      const int n = (wn * 5 + n5) * 16 + lc;
      const float cv = isP ? ((n < 132) ? pb1[n] : 0.f) : e1q[b * 160 + n];
      #pragma unroll
      for (int r = 0; r < 4; ++r) acc[mi2][n5][r] = cv;
    }

  for (int c = 0; c < 4; ++c) {
    __syncthreads();
    for (int o = t; o < 1024; o += 256) {
      const int rr = o >> 4, kq = o & 15;
      f32x4 v = {0.f, 0.f, 0.f, 0.f};
      if (isP) {
        if (rr < 8) {
          const float* s = (c < 2) ? (qmax + rr * 128 + c * 64) : (P + rr * 128 + (c - 2) * 64);
          v = *(const f32x4*)(s + kq * 4);
        }
      } else {
        const size_t rowg = (size_t)(b * 128 + x0 + rr);
        const float* s = (c < 2) ? (Q + rowg * 128 + c * 64)
                                 : (((c == 2) ? red0 : red1) + rowg * 64);
        v = *(const f32x4*)(s + kq * 4);
      }
      f16x4 hv;
      hv[0] = (f16)v[0]; hv[1] = (f16)v[1]; hv[2] = (f16)v[2]; hv[3] = (f16)v[3];
      *(f16x4*)(&Xc[rr][kq * 4]) = hv;
    }
    __syncthreads();
    #pragma unroll
    for (int kk = 0; kk < 2; ++kk) {
      f16x8 a[2];
      #pragma unroll
      for (int mi2 = 0; mi2 < 2; ++mi2)
        a[mi2] = *(const f16x8*)(&Xc[rb + mi2 * 16 + lc][kk * 32 + lk]);
      const int kg = c * 2 + kk;
      #pragma unroll
      for (int n5 = 0; n5 < 5; ++n5) {
        const f16x8 bf = *(const f16x8*)(&Wb[(kg * 10 + wn * 5 + n5) * 512 + lane * 8]);
        #pragma unroll
        for (int mi2 = 0; mi2 < 2; ++mi2)
          acc[mi2][n5] = MFMA16(a[mi2], bf, acc[mi2][n5]);
      }
    }
  }
  #pragma unroll
  for (int mi2 = 0; mi2 < 2; ++mi2)
    #pragma unroll
    for (int n5 = 0; n5 < 5; ++n5)
      #pragma unroll
      for (int r = 0; r < 4; ++r)
        Hs2[rb + mi2 * 16 + lr + r][(wn * 5 + n5) * 16 + lc] = (f16)fmaxf(acc[mi2][n5][r], 0.f);
  __syncthreads();   // all Wb(L1) reads + Hs2 writes complete

  // stage L2 (50 frags) + L3 (20 frags) weights into Wb
  for (int f = w; f < 50; f += 4)
    *(f16x8*)(&Wb[f * 512 + lane * 8]) = *(const f16x8*)(W2g + (size_t)f * 512 + lane * 8);
  for (int f = w; f < 20; f += 4)
    *(f16x8*)(&Wb[(50 + f) * 512 + lane * 8]) = *(const f16x8*)(W3g + (size_t)f * 512 + lane * 8);

  // L2 acc init
  #pragma unroll
  for (int mi2 = 0; mi2 < 2; ++mi2)
    #pragma unroll
    for (int n5 = 0; n5 < 5; ++n5) {
      const int n = (wn * 5 + n5) * 16 + lc;
      const float bv = (n < 132) ? (isP ? pb2[n] : qb2[n]) : 0.f;
      #pragma unroll
      for (int r = 0; r < 4; ++r) acc[mi2][n5][r] = bv;
    }
  __syncthreads();
  #pragma unroll
  for (int kk = 0; kk < 5; ++kk) {
    f16x8 a[2];
    #pragma unroll
    for (int mi2 = 0; mi2 < 2; ++mi2)
      a[mi2] = *(const f16x8*)(&Hs2[rb + mi2 * 16 + lc][kk * 32 + lk]);
    #pragma unroll
    for (int n5 = 0; n5 < 5; ++n5) {
      const f16x8 bf = *(const f16x8*)(&Wb[(kk * 10 + wn * 5 + n5) * 512 + lane * 8]);
      #pragma unroll
      for (int mi2 = 0; mi2 < 2; ++mi2)
        acc[mi2][n5] = MFMA16(a[mi2], bf, acc[mi2][n5]);
    }
  }
  __syncthreads();   // all Hs2(L1) reads complete before overwrite
  #pragma unroll
  for (int mi2 = 0; mi2 < 2; ++mi2)
    #pragma unroll
    for (int n5 = 0; n5 < 5; ++n5)
      #pragma unroll
      for (int r = 0; r < 4; ++r)
        Hs2[rb + mi2 * 16 + lr + r][(wn * 5 + n5) * 16 + lc] = (f16)fmaxf(acc[mi2][n5][r], 0.f);
  __syncthreads();

  // L3
  f32x4 acc3[2][2];
  #pragma unroll
  for (int mi2 = 0; mi2 < 2; ++mi2)
    #pragma unroll
    for (int j2 = 0; j2 < 2; ++j2) {
      const int n = (wn * 2 + j2) * 16 + lc;
      const float bv = isP ? pb3[n] : qb3[n];
      #pragma unroll
      for (int r = 0; r < 4; ++r) acc3[mi2][j2][r] = bv;
    }
  #pragma unroll
  for (int kk = 0; kk < 5; ++kk) {
    f16x8 a[2];
    #pragma unroll
    for (int mi2 = 0; mi2 < 2; ++mi2)
      a[mi2] = *(const f16x8*)(&Hs2[rb + mi2 * 16 + lc][kk * 32 + lk]);
    #pragma unroll
    for (int j2 = 0; j2 < 2; ++j2) {
      const f16x8 bf = *(const f16x8*)(&Wb[(50 + kk * 4 + wn * 2 + j2) * 512 + lane * 8]);
      #pragma unroll
      for (int mi2 = 0; mi2 < 2; ++mi2)
        acc3[mi2][j2] = MFMA16(a[mi2], bf, acc3[mi2][j2]);
    }
  }
  #pragma unroll
  for (int mi2 = 0; mi2 < 2; ++mi2)
    #pragma unroll
    for (int j2 = 0; j2 < 2; ++j2)
      #pragma unroll
      for (int r = 0; r < 4; ++r) {
        const int rr = rb + mi2 * 16 + lr + r;
        const int n = (wn * 2 + j2) * 16 + lc;
        const float s = 1.f / (1.f + __expf(-5.f * acc3[mi2][j2][r]));
        if (isP) {
          if (rr < 8) outP[rr * 64 + n] = s;
        } else {
          outQ[((size_t)(b * 128 + x0 + rr)) * 64 + n] = s;
        }
      }
}

extern "C" void kernel_launch(void* const* d_in, const int* in_sizes, int n_in,
                              void* d_out, int out_size, void* d_ws, size_t ws_size,
                              hipStream_t stream) {
  (void)in_sizes; (void)n_in; (void)out_size; (void)ws_size;
  InPtrs ip;
  for (int i = 0; i < 21; ++i) ip.p[i] = (const float*)d_in[i];

  char* ws = (char*)d_ws;
  f16* wpk = (f16*)ws;
  float* wsf = (float*)(ws + PACK_BYTES);
  float* c1 = wsf;
  float* d1 = wsf + 163840;
  float* e1q = wsf + 327680;
  float* qmax = wsf + 328960;
  float* red0 = wsf + 329984;
  float* red1 = wsf + 395520;

  float* outP = (float*)d_out;
  float* outQ = outP + 512;
  float* outR = outP + 66048;

  prep_kernel<<<dim3(PREP_BLOCKS), dim3(256), 0, stream>>>(ip, wpk, c1, d1, e1q, qmax, red0, red1);
  mainR_kernel<<<dim3(1024), dim3(256), 0, stream>>>((const float*)d_in[2], c1, d1,
      (const float*)d_in[18], (const float*)d_in[20], wpk, outR);
  small_kernel<<<dim3(17), dim3(256), 0, stream>>>((const float*)d_in[0], (const float*)d_in[1],
      (const float*)d_in[12], (const float*)d_in[14],
      (const float*)d_in[4], (const float*)d_in[6], (const float*)d_in[8],
      wpk, e1q, qmax, red0, red1, outP, outQ);
}

// Round 4
// 73.553 us; speedup vs baseline: 2.1872x; 1.0011x over previous
//
#include <hip/hip_runtime.h>

typedef _Float16 f16;
typedef f16 f16x8 __attribute__((ext_vector_type(8)));
typedef f16 f16x4 __attribute__((ext_vector_type(4)));
typedef float f32x4 __attribute__((ext_vector_type(4)));

#define MFMA16(a, b, c) __builtin_amdgcn_mfma_f32_16x16x32_f16(a, b, c, 0, 0, 0)

// packed-weight offsets in f16 elements within d_ws
#define OFF_RW1A 0
#define OFF_RW2  10240
#define OFF_RW3  35840
#define OFF_QW1  46080
#define OFF_QW2  87040
#define OFF_QW3  112640
#define OFF_PW1  122880
#define OFF_PW2  163840
#define OFF_PW3  189440
#define PACK_BYTES 399360   // 199680 f16

// prep grid: [0,1024) red0 | [1024,1123) pack | [1123,1131) qmax
//            [1131,1139) e1q | [1139,1395) c1/d1 | [1395,2419) red1
#define PREP_BLOCKS 2419

struct InPtrs { const float* p[21]; };

__device__ const int g_mSrc[9] = {15, 17, 19, 9, 11, 13, 3, 5, 7};
__device__ const int g_mK0[9]  = {0, 0, 0, 128, 0, 0, 0, 0, 0};
__device__ const int g_mK[9]   = {64, 132, 132, 256, 132, 132, 256, 132, 132};
__device__ const int g_mN[9]   = {132, 132, 64, 132, 132, 64, 132, 132, 64};
__device__ const int g_mNT[9]  = {10, 10, 4, 10, 10, 4, 10, 10, 4};
__device__ const int g_mDst[9] = {OFF_RW1A, OFF_RW2, OFF_RW3, OFF_QW1, OFF_QW2, OFF_QW3,
                                  OFF_PW1, OFF_PW2, OFF_PW3};
__device__ const int g_mBlk0[9] = {1024, 1029, 1042, 1047, 1067, 1080, 1085, 1105, 1118};

__global__ __launch_bounds__(256) void prep_kernel(InPtrs in, f16* __restrict__ wpk,
    float* __restrict__ c1, float* __restrict__ d1, float* __restrict__ e1q,
    float* __restrict__ qmax, float* __restrict__ red0, float* __restrict__ red1)
{
  __shared__ float sbuf[1024];
  const int mb = blockIdx.x, t = threadIdx.x;

  if (mb < 1024) {
    // red0[b,j,d] = max_i R[b,i,j,d]; one block per (b,j); strided i.
    const int b = mb >> 7, j = mb & 127;
    const float* base = in.p[2] + (size_t)b * 128 * 8192 + (size_t)j * 64 + (t & 15) * 4;
    const int g = t >> 4;
    f32x4 mm[8];
    #pragma unroll
    for (int v = 0; v < 8; ++v)
      mm[v] = *(const f32x4*)(base + (size_t)(g + 16 * v) * 8192);
    #pragma unroll
    for (int s = 4; s > 0; s >>= 1)
      #pragma unroll
      for (int v = 0; v < 4; ++v)
        if (v < s) {
          mm[v][0] = fmaxf(mm[v][0], mm[v + s][0]);
          mm[v][1] = fmaxf(mm[v][1], mm[v + s][1]);
          mm[v][2] = fmaxf(mm[v][2], mm[v + s][2]);
          mm[v][3] = fmaxf(mm[v][3], mm[v + s][3]);
        }
    float* sr = sbuf + g * 64 + (t & 15) * 4;
    sr[0] = mm[0][0]; sr[1] = mm[0][1]; sr[2] = mm[0][2]; sr[3] = mm[0][3];
    __syncthreads();
    if (t < 64) {
      float m = sbuf[t];
      #pragma unroll
      for (int g2 = 1; g2 < 16; ++g2) m = fmaxf(m, sbuf[g2 * 64 + t]);
      red0[(size_t)mb * 64 + t] = m;
    }
  } else if (mb < 1123) {
    // weight pack into MFMA B-fragment layout
    int mi = 8;
    while (mi > 0 && mb < g_mBlk0[mi]) --mi;
    const int NT = g_mNT[mi], K = g_mK[mi], N = g_mN[mi], K0 = g_mK0[mi];
    const int L = (mb - g_mBlk0[mi]) * 256 + t;
    const int lanes = ((K + 31) >> 5) * NT * 64;
    if (L < lanes) {
      const int lane = L & 63, tile = L >> 6;
      const int kk = tile / NT, nn = tile % NT;
      const float* src = in.p[g_mSrc[mi]];
      const int n = nn * 16 + (lane & 15);
      const int kb = kk * 32 + ((lane >> 4) << 3);
      f16x8 v;
      #pragma unroll
      for (int u = 0; u < 8; ++u) {
        const int k = kb + u;
        float f = (k < K && n < N) ? src[(size_t)(K0 + k) * N + n] : 0.f;
        v[u] = (f16)f;
      }
      *(f16x8*)(wpk + g_mDst[mi] + (size_t)L * 8) = v;
    }
  } else if (mb < 1131) {
    // qmax[b,d] = max_i Q[b,i,d]
    const int b = mb - 1123;
    const float* Qb = in.p[1] + (size_t)b * 128 * 128;
    const int d = t & 127, g = t >> 7;
    float m0 = -3.4e38f, m1 = m0, m2 = m0, m3 = m0;
    #pragma unroll
    for (int v = 0; v < 16; ++v) {
      const int i = g * 64 + v * 4;
      m0 = fmaxf(m0, Qb[(size_t)(i + 0) * 128 + d]);
      m1 = fmaxf(m1, Qb[(size_t)(i + 1) * 128 + d]);
      m2 = fmaxf(m2, Qb[(size_t)(i + 2) * 128 + d]);
      m3 = fmaxf(m3, Qb[(size_t)(i + 3) * 128 + d]);
    }
    sbuf[g * 128 + d] = fmaxf(fmaxf(m0, m1), fmaxf(m2, m3));
    __syncthreads();
    if (t < 128) qmax[b * 128 + t] = fmaxf(sbuf[t], sbuf[128 + t]);
  } else if (mb < 1139) {
    // e1q[b,n] = P[b] . q_w1[0:128] + q_b1
    const int b = mb - 1131;
    const float* P = in.p[0]; const float* qw1 = in.p[9]; const float* qb1 = in.p[10];
    if (t < 160) {
      float a = 0.f;
      if (t < 132) {
        float a0 = 0.f, a1 = 0.f, a2 = 0.f, a3 = 0.f;
        for (int k = 0; k < 128; k += 4) {
          a0 += P[b * 128 + k + 0] * qw1[(size_t)(k + 0) * 132 + t];
          a1 += P[b * 128 + k + 1] * qw1[(size_t)(k + 1) * 132 + t];
          a2 += P[b * 128 + k + 2] * qw1[(size_t)(k + 2) * 132 + t];
          a3 += P[b * 128 + k + 3] * qw1[(size_t)(k + 3) * 132 + t];
        }
        a = qb1[t] + (a0 + a1) + (a2 + a3);
      }
      e1q[b * 160 + t] = a;
    }
  } else if (mb < 1395) {
    // c1/d1 (r-branch folded Q contributions), 4 Q-rows per block
    const int blk = mb - 1139;
    const float* Q = in.p[1]; const float* rw1 = in.p[15]; const float* rb1 = in.p[16];
    for (int o = t; o < 512; o += 256) sbuf[o] = Q[(size_t)blk * 512 + o];
    __syncthreads();
    if (t < 160) {
      float cc[4], dd[4];
      #pragma unroll
      for (int r = 0; r < 4; ++r) { cc[r] = 0.f; dd[r] = 0.f; }
      if (t < 132) {
        const float bb = rb1[t];
        #pragma unroll
        for (int r = 0; r < 4; ++r) cc[r] = bb;
        for (int k = 0; k < 128; ++k) {
          const float wc = rw1[(size_t)(192 + k) * 132 + t];
          const float wd = rw1[(size_t)(64 + k) * 132 + t];
          #pragma unroll
          for (int r = 0; r < 4; ++r) {
            cc[r] += sbuf[r * 128 + k] * wc;
            dd[r] += sbuf[r * 128 + k] * wd;
          }
        }
      }
      for (int r = 0; r < 4; ++r) {
        c1[(size_t)(blk * 4 + r) * 160 + t] = cc[r];
        d1[(size_t)(blk * 4 + r) * 160 + t] = dd[r];
      }
    }
  } else {
    // red1[b,i,d] = max_j R[b,i,j,d]; one block per (b,i); contiguous j.
    const int blk = mb - 1395;
    const float* base = in.p[2] + (size_t)blk * 8192 + (t & 15) * 4;
    const int g = t >> 4;
    f32x4 mm[8];
    #pragma unroll
    for (int v = 0; v < 8; ++v)
      mm[v] = *(const f32x4*)(base + (size_t)(g + 16 * v) * 64);
    #pragma unroll
    for (int s = 4; s > 0; s >>= 1)
      #pragma unroll
      for (int v = 0; v < 4; ++v)
        if (v < s) {
          mm[v][0] = fmaxf(mm[v][0], mm[v + s][0]);
          mm[v][1] = fmaxf(mm[v][1], mm[v + s][1]);
          mm[v][2] = fmaxf(mm[v][2], mm[v + s][2]);
          mm[v][3] = fmaxf(mm[v][3], mm[v + s][3]);
        }
    float* sr = sbuf + g * 64 + (t & 15) * 4;
    sr[0] = mm[0][0]; sr[1] = mm[0][1]; sr[2] = mm[0][2]; sr[3] = mm[0][3];
    __syncthreads();
    if (t < 64) {
      float m = sbuf[t];
      #pragma unroll
      for (int g2 = 1; g2 < 16; ++g2) m = fmaxf(m, sbuf[g2 * 64 + t]);
      red1[(size_t)blk * 64 + t] = m;
    }
  }
}

__device__ __forceinline__ float sig5(float x) {
  return 1.f / (1.f + __expf(-5.f * x));
}

// ---------------------------------------------------------------------------
// fused kernel: blocks [0,1024) = R branch (one per (b,i));
//               blocks [1024,1040) = Q branch; block 1040 = P branch.
// All MFMAs use swapped operands: D = W^T . X^T, so each lane owns 4
// CONSECUTIVE n for one j -> b64 H-stores, f32x4 acc-init, dwordx4 epilogue.
// ---------------------------------------------------------------------------
__global__ __launch_bounds__(256, 2) void fused_kernel(
    const float* __restrict__ R, const float* __restrict__ c1, const float* __restrict__ d1,
    const float* __restrict__ rb2, const float* __restrict__ rb3,
    const f16* __restrict__ wpk, float* __restrict__ outR,
    const float* __restrict__ P, const float* __restrict__ Q,
    const float* __restrict__ qb2, const float* __restrict__ qb3,
    const float* __restrict__ pb1, const float* __restrict__ pb2, const float* __restrict__ pb3,
    const float* __restrict__ e1q, const float* __restrict__ qmax,
    const float* __restrict__ red0, const float* __restrict__ red1,
    float* __restrict__ outP, float* __restrict__ outQ)
{
  __shared__ __align__(16) char pool[81920];   // 80 KB -> 2 blocks/CU
  const int blk = blockIdx.x;
  const int t = threadIdx.x, lane = t & 63, w = t >> 6;
  const int wm = w >> 1, wn = w & 1;
  const int lr = (lane >> 4) << 2;   // D row group (n within 16-tile)
  const int lc = lane & 15;          // D col (j within 16-tile) / frag m-n index
  const int lk = (lane >> 4) << 3;   // A/B-frag k offset

  if (blk < 1024) {
    // ================= R branch =================
    f16 (*Xr)[72]  = (f16(*)[72])pool;                 // 18432 B
    f16 (*Hs)[168] = (f16(*)[168])(pool + 18432);      // 43008 B
    const int rbase = wm * 64, nbase = wn * 80;

    const float* Rb = R + (size_t)blk * 8192;
    #pragma unroll
    for (int v = 0; v < 8; ++v) {
      const int quad = v * 256 + t;
      const int j = quad >> 4, kq = quad & 15;
      f32x4 rv = *(const f32x4*)(Rb + (size_t)j * 64 + kq * 4);
      f16x4 hv;
      hv[0] = (f16)rv[0]; hv[1] = (f16)rv[1]; hv[2] = (f16)rv[2]; hv[3] = (f16)rv[3];
      *(f16x4*)(&Xr[j][kq * 4]) = hv;
    }

    // ---- L1: acc init from c1 + d1 (all f32x4) ----
    const int b = blk >> 7;
    const float* c1r = c1 + (size_t)blk * 160;
    const float* d1b = d1 + (size_t)b * 128 * 160;
    f32x4 acc[4][5];
    f32x4 cvv[5];
    #pragma unroll
    for (int n5 = 0; n5 < 5; ++n5)
      cvv[n5] = *(const f32x4*)(c1r + nbase + n5 * 16 + lr);
    #pragma unroll
    for (int mi2 = 0; mi2 < 4; ++mi2) {
      const int j = rbase + mi2 * 16 + lc;
      #pragma unroll
      for (int n5 = 0; n5 < 5; ++n5) {
        f32x4 dv = *(const f32x4*)(d1b + (size_t)j * 160 + nbase + n5 * 16 + lr);
        acc[mi2][n5] = cvv[n5] + dv;
      }
    }
    __syncthreads();
    const f16x8* W1p = (const f16x8*)(wpk + OFF_RW1A);
    #pragma unroll
    for (int kk = 0; kk < 2; ++kk) {
      f16x8 a[4];
      #pragma unroll
      for (int mi2 = 0; mi2 < 4; ++mi2)
        a[mi2] = *(const f16x8*)(&Xr[rbase + mi2 * 16 + lc][kk * 32 + lk]);
      #pragma unroll
      for (int n5 = 0; n5 < 5; ++n5) {
        const f16x8 bf = W1p[(size_t)(kk * 10 + wn * 5 + n5) * 64 + lane];
        #pragma unroll
        for (int mi2 = 0; mi2 < 4; ++mi2)
          acc[mi2][n5] = MFMA16(bf, a[mi2], acc[mi2][n5]);
      }
    }
    #pragma unroll
    for (int mi2 = 0; mi2 < 4; ++mi2) {
      const int j = rbase + mi2 * 16 + lc;
      #pragma unroll
      for (int n5 = 0; n5 < 5; ++n5) {
        f16x4 hv;
        #pragma unroll
        for (int r = 0; r < 4; ++r) hv[r] = (f16)fmaxf(acc[mi2][n5][r], 0.f);
        *(f16x4*)(&Hs[j][nbase + n5 * 16 + lr]) = hv;
      }
    }
    __syncthreads();

    // ---- L2 ----
    #pragma unroll
    for (int n5 = 0; n5 < 5; ++n5) {
      const int nb = nbase + n5 * 16 + lr;
      f32x4 bv = {0.f, 0.f, 0.f, 0.f};
      if (nb < 132) bv = *(const f32x4*)(rb2 + nb);
      #pragma unroll
      for (int mi2 = 0; mi2 < 4; ++mi2) acc[mi2][n5] = bv;
    }
    const f16x8* W2p = (const f16x8*)(wpk + OFF_RW2);
    #pragma unroll
    for (int kk = 0; kk < 5; ++kk) {
      f16x8 a[4];
      #pragma unroll
      for (int mi2 = 0; mi2 < 4; ++mi2)
        a[mi2] = *(const f16x8*)(&Hs[rbase + mi2 * 16 + lc][kk * 32 + lk]);
      #pragma unroll
      for (int n5 = 0; n5 < 5; ++n5) {
        const f16x8 bf = W2p[(size_t)(kk * 10 + wn * 5 + n5) * 64 + lane];
        #pragma unroll
        for (int mi2 = 0; mi2 < 4; ++mi2)
          acc[mi2][n5] = MFMA16(bf, a[mi2], acc[mi2][n5]);
      }
    }
    __syncthreads();
    #pragma unroll
    for (int mi2 = 0; mi2 < 4; ++mi2) {
      const int j = rbase + mi2 * 16 + lc;
      #pragma unroll
      for (int n5 = 0; n5 < 5; ++n5) {
        f16x4 hv;
        #pragma unroll
        for (int r = 0; r < 4; ++r) hv[r] = (f16)fmaxf(acc[mi2][n5][r], 0.f);
        *(f16x4*)(&Hs[j][nbase + n5 * 16 + lr]) = hv;
      }
    }
    __syncthreads();

    // ---- L3 ----
    f32x4 acc3[4][2];
    const int n3base = wn * 32;
    #pragma unroll
    for (int n2 = 0; n2 < 2; ++n2) {
      f32x4 bv = *(const f32x4*)(rb3 + n3base + n2 * 16 + lr);
      #pragma unroll
      for (int mi2 = 0; mi2 < 4; ++mi2) acc3[mi2][n2] = bv;
    }
    const f16x8* W3p = (const f16x8*)(wpk + OFF_RW3);
    #pragma unroll
    for (int kk = 0; kk < 5; ++kk) {
      f16x8 a[4];
      #pragma unroll
      for (int mi2 = 0; mi2 < 4; ++mi2)
        a[mi2] = *(const f16x8*)(&Hs[rbase + mi2 * 16 + lc][kk * 32 + lk]);
      #pragma unroll
      for (int n2 = 0; n2 < 2; ++n2) {
        const f16x8 bf = W3p[(size_t)(kk * 4 + wn * 2 + n2) * 64 + lane];
        #pragma unroll
        for (int mi2 = 0; mi2 < 4; ++mi2)
          acc3[mi2][n2] = MFMA16(bf, a[mi2], acc3[mi2][n2]);
      }
    }
    float* Ro = outR + (size_t)blk * 8192;
    #pragma unroll
    for (int mi2 = 0; mi2 < 4; ++mi2) {
      const int j = rbase + mi2 * 16 + lc;
      #pragma unroll
      for (int n2 = 0; n2 < 2; ++n2) {
        f32x4 ov;
        #pragma unroll
        for (int r = 0; r < 4; ++r) ov[r] = sig5(acc3[mi2][n2][r]);
        *(f32x4*)(Ro + (size_t)j * 64 + n3base + n2 * 16 + lr) = ov;
      }
    }
  } else {
    // ================= Q / P branch =================
    f16 (*Xc)[72]  = (f16(*)[72])pool;                 //  9216 B
    f16 (*Hs2)[168] = (f16(*)[168])(pool + 9216);      // 21504 B
    f16* Wb = (f16*)(pool + 30720);                    // 51200 B (50 frags)
    const int bs = blk - 1024;
    const bool isP = (bs == 16);
    const int rb = wm * 32;
    const int b = bs >> 1, x0 = (bs & 1) * 64;
    const f16* W1g = wpk + (isP ? OFF_PW1 : OFF_QW1);
    const f16* W2g = wpk + (isP ? OFF_PW2 : OFF_QW2);
    const f16* W3g = wpk + (isP ? OFF_PW3 : OFF_QW3);

    f32x4 acc[2][5];
    #pragma unroll
    for (int n5 = 0; n5 < 5; ++n5) {
      const int nb = wn * 80 + n5 * 16 + lr;
      f32x4 cv = {0.f, 0.f, 0.f, 0.f};
      if (isP) { if (nb < 132) cv = *(const f32x4*)(pb1 + nb); }
      else cv = *(const f32x4*)(e1q + b * 160 + nb);
      acc[0][n5] = cv; acc[1][n5] = cv;
    }

    for (int c = 0; c < 4; ++c) {
      // stage half of W1 at c==0 / c==2 (frags [half*40, half*40+40))
      if ((c & 1) == 0) {
        const int half = c >> 1;
        for (int idx = t; idx < 40 * 64; idx += 256) {
          const int f = idx >> 6, ln = idx & 63;
          *(f16x8*)(&Wb[f * 512 + ln * 8]) =
              *(const f16x8*)(W1g + (size_t)(half * 40 + f) * 512 + ln * 8);
        }
      }
      // stage X chunk c
      for (int o = t; o < 1024; o += 256) {
        const int rr = o >> 4, kq = o & 15;
        f32x4 v = {0.f, 0.f, 0.f, 0.f};
        if (isP) {
          if (rr < 8) {
            const float* s = (c < 2) ? (qmax + rr * 128 + c * 64) : (P + rr * 128 + (c - 2) * 64);
            v = *(const f32x4*)(s + kq * 4);
          }
        } else {
          const size_t rowg = (size_t)(b * 128 + x0 + rr);
          const float* s = (c < 2) ? (Q + rowg * 128 + c * 64)
                                   : (((c == 2) ? red0 : red1) + rowg * 64);
          v = *(const f32x4*)(s + kq * 4);
        }
        f16x4 hv;
        hv[0] = (f16)v[0]; hv[1] = (f16)v[1]; hv[2] = (f16)v[2]; hv[3] = (f16)v[3];
        *(f16x4*)(&Xc[rr][kq * 4]) = hv;
      }
      __syncthreads();
      #pragma unroll
      for (int kk = 0; kk < 2; ++kk) {
        f16x8 a[2];
        #pragma unroll
        for (int mi2 = 0; mi2 < 2; ++mi2)
          a[mi2] = *(const f16x8*)(&Xc[rb + mi2 * 16 + lc][kk * 32 + lk]);
        #pragma unroll
        for (int n5 = 0; n5 < 5; ++n5) {
          const int rel = ((c & 1) * 2 + kk) * 10 + wn * 5 + n5;
          const f16x8 bf = *(const f16x8*)(&Wb[rel * 512 + lane * 8]);
          #pragma unroll
          for (int mi2 = 0; mi2 < 2; ++mi2)
            acc[mi2][n5] = MFMA16(bf, a[mi2], acc[mi2][n5]);
        }
      }
      __syncthreads();   // X / W1-half reads done before restage
    }
    #pragma unroll
    for (int mi2 = 0; mi2 < 2; ++mi2) {
      const int j = rb + mi2 * 16 + lc;
      #pragma unroll
      for (int n5 = 0; n5 < 5; ++n5) {
        f16x4 hv;
        #pragma unroll
        for (int r = 0; r < 4; ++r) hv[r] = (f16)fmaxf(acc[mi2][n5][r], 0.f);
        *(f16x4*)(&Hs2[j][wn * 80 + n5 * 16 + lr]) = hv;
      }
    }
    // stage all 50 W2 frags + L2 acc init
    for (int idx = t; idx < 50 * 64; idx += 256) {
      const int f = idx >> 6, ln = idx & 63;
      *(f16x8*)(&Wb[f * 512 + ln * 8]) = *(const f16x8*)(W2g + (size_t)f * 512 + ln * 8);
    }
    #pragma unroll
    for (int n5 = 0; n5 < 5; ++n5) {
      const int nb = wn * 80 + n5 * 16 + lr;
      f32x4 bv = {0.f, 0.f, 0.f, 0.f};
      if (nb < 132) bv = *(const f32x4*)((isP ? pb2 : qb2) + nb);
      acc[0][n5] = bv; acc[1][n5] = bv;
    }
    __syncthreads();   // H1 + W2 visible
    #pragma unroll
    for (int kk = 0; kk < 5; ++kk) {
      f16x8 a[2];
      #pragma unroll
      for (int mi2 = 0; mi2 < 2; ++mi2)
        a[mi2] = *(const f16x8*)(&Hs2[rb + mi2 * 16 + lc][kk * 32 + lk]);
      #pragma unroll
      for (int n5 = 0; n5 < 5; ++n5) {
        const f16x8 bf = *(const f16x8*)(&Wb[(kk * 10 + wn * 5 + n5) * 512 + lane * 8]);
        #pragma unroll
        for (int mi2 = 0; mi2 < 2; ++mi2)
          acc[mi2][n5] = MFMA16(bf, a[mi2], acc[mi2][n5]);
      }
    }
    __syncthreads();   // all H1/W2 reads done
    #pragma unroll
    for (int mi2 = 0; mi2 < 2; ++mi2) {
      const int j = rb + mi2 * 16 + lc;
      #pragma unroll
      for (int n5 = 0; n5 < 5; ++n5) {
        f16x4 hv;
        #pragma unroll
        for (int r = 0; r < 4; ++r) hv[r] = (f16)fmaxf(acc[mi2][n5][r], 0.f);
        *(f16x4*)(&Hs2[j][wn * 80 + n5 * 16 + lr]) = hv;
      }
    }
    for (int idx = t; idx < 20 * 64; idx += 256) {
      const int f = idx >> 6, ln = idx & 63;
      *(f16x8*)(&Wb[f * 512 + ln * 8]) = *(const f16x8*)(W3g + (size_t)f * 512 + ln * 8);
    }
    __syncthreads();

    // L3
    f32x4 acc3[2][2];
    const int n3base = wn * 32;
    #pragma unroll
    for (int n2 = 0; n2 < 2; ++n2) {
      f32x4 bv = *(const f32x4*)((isP ? pb3 : qb3) + n3base + n2 * 16 + lr);
      acc3[0][n2] = bv; acc3[1][n2] = bv;
    }
    #pragma unroll
    for (int kk = 0; kk < 5; ++kk) {
      f16x8 a[2];
      #pragma unroll
      for (int mi2 = 0; mi2 < 2; ++mi2)
        a[mi2] = *(const f16x8*)(&Hs2[rb + mi2 * 16 + lc][kk * 32 + lk]);
      #pragma unroll
      for (int n2 = 0; n2 < 2; ++n2) {
        const f16x8 bf = *(const f16x8*)(&Wb[(kk * 4 + wn * 2 + n2) * 512 + lane * 8]);
        #pragma unroll
        for (int mi2 = 0; mi2 < 2; ++mi2)
          acc3[mi2][n2] = MFMA16(bf, a[mi2], acc3[mi2][n2]);
      }
    }
    #pragma unroll
    for (int mi2 = 0; mi2 < 2; ++mi2) {
      const int j = rb + mi2 * 16 + lc;
      #pragma unroll
      for (int n2 = 0; n2 < 2; ++n2) {
        f32x4 ov;
        #pragma unroll
        for (int r = 0; r < 4; ++r) ov[r] = sig5(acc3[mi2][n2][r]);
        if (isP) {
          if (j < 8) *(f32x4*)(outP + (size_t)j * 64 + n3base + n2 * 16 + lr) = ov;
        } else {
          *(f32x4*)(outQ + ((size_t)(b * 128 + x0 + j)) * 64 + n3base + n2 * 16 + lr) = ov;
        }
      }
    }
  }
}

extern "C" void kernel_launch(void* const* d_in, const int* in_sizes, int n_in,
                              void* d_out, int out_size, void* d_ws, size_t ws_size,
                              hipStream_t stream) {
  (void)in_sizes; (void)n_in; (void)out_size; (void)ws_size;
  InPtrs ip;
  for (int i = 0; i < 21; ++i) ip.p[i] = (const float*)d_in[i];

  char* ws = (char*)d_ws;
  f16* wpk = (f16*)ws;
  float* wsf = (float*)(ws + PACK_BYTES);
  float* c1 = wsf;
  float* d1 = wsf + 163840;
  float* e1q = wsf + 327680;
  float* qmax = wsf + 328960;
  float* red0 = wsf + 329984;
  float* red1 = wsf + 395520;

  float* outP = (float*)d_out;
  float* outQ = outP + 512;
  float* outR = outP + 66048;

  prep_kernel<<<dim3(PREP_BLOCKS), dim3(256), 0, stream>>>(ip, wpk, c1, d1, e1q, qmax, red0, red1);
  fused_kernel<<<dim3(1041), dim3(256), 0, stream>>>((const float*)d_in[2], c1, d1,
      (const float*)d_in[18], (const float*)d_in[20], wpk, outR,
      (const float*)d_in[0], (const float*)d_in[1],
      (const float*)d_in[12], (const float*)d_in[14],
      (const float*)d_in[4], (const float*)d_in[6], (const float*)d_in[8],
      e1q, qmax, red0, red1, outP, outQ);
}

// Round 5
// 64.461 us; speedup vs baseline: 2.4957x; 1.1410x over previous
//
#include <hip/hip_runtime.h>

typedef _Float16 f16;
typedef f16 f16x8 __attribute__((ext_vector_type(8)));
typedef f16 f16x4 __attribute__((ext_vector_type(4)));
typedef float f32x4 __attribute__((ext_vector_type(4)));
typedef float f32x2 __attribute__((ext_vector_type(2)));

#define MFMA16(a, b, c) __builtin_amdgcn_mfma_f32_16x16x32_f16(a, b, c, 0, 0, 0)

// packed-weight offsets in f16 elements within d_ws
#define OFF_RW1A 0
#define OFF_RW2  10240
#define OFF_RW3  35840
#define OFF_QW1  46080
#define OFF_QW2  87040
#define OFF_QW3  112640
#define OFF_PW1  122880
#define OFF_PW2  163840
#define OFF_PW3  189440
#define PACK_BYTES 399360   // 199680 f16

// prep grid: [0,128) red0 | [128,227) pack | [227,235) qmax
//            [235,243) e1q | [243,499) c1/d1 | [499,1523) red1
#define PREP_BLOCKS 1523

struct InPtrs { const float* p[21]; };

__device__ const int g_mSrc[9] = {15, 17, 19, 9, 11, 13, 3, 5, 7};
__device__ const int g_mK0[9]  = {0, 0, 0, 128, 0, 0, 0, 0, 0};
__device__ const int g_mK[9]   = {64, 132, 132, 256, 132, 132, 256, 132, 132};
__device__ const int g_mN[9]   = {132, 132, 64, 132, 132, 64, 132, 132, 64};
__device__ const int g_mNT[9]  = {10, 10, 4, 10, 10, 4, 10, 10, 4};
__device__ const int g_mDst[9] = {OFF_RW1A, OFF_RW2, OFF_RW3, OFF_QW1, OFF_QW2, OFF_QW3,
                                  OFF_PW1, OFF_PW2, OFF_PW3};
__device__ const int g_mBlk0[9] = {128, 133, 146, 151, 171, 184, 189, 209, 222};

__global__ __launch_bounds__(256) void prep_kernel(InPtrs in, f16* __restrict__ wpk,
    float* __restrict__ c1, float* __restrict__ d1, float* __restrict__ e1q,
    float* __restrict__ qmax, float* __restrict__ red0, float* __restrict__ red1)
{
  __shared__ float sbuf[1024];
  const int mb = blockIdx.x, t = threadIdx.x;

  if (mb < 128) {
    // red0[b,j,d] = max_i R[b,i,j,d]; block = (b, j-oct). Per i: 2KB contiguous.
    const int b = mb >> 4, jo = mb & 15;
    const float* base = in.p[2] + (size_t)b * 1048576 + (size_t)jo * 512 + t * 2;
    f32x2 m[8];
    #pragma unroll
    for (int u = 0; u < 8; ++u) { m[u][0] = -3.4e38f; m[u][1] = -3.4e38f; }
    for (int i = 0; i < 128; i += 8) {
      #pragma unroll
      for (int u = 0; u < 8; ++u) {
        f32x2 v = *(const f32x2*)(base + (size_t)(i + u) * 8192);
        m[u][0] = fmaxf(m[u][0], v[0]);
        m[u][1] = fmaxf(m[u][1], v[1]);
      }
    }
    #pragma unroll
    for (int s = 4; s > 0; s >>= 1)
      #pragma unroll
      for (int u = 0; u < 4; ++u)
        if (u < s) {
          m[u][0] = fmaxf(m[u][0], m[u + s][0]);
          m[u][1] = fmaxf(m[u][1], m[u + s][1]);
        }
    *(f32x2*)(red0 + ((size_t)(b * 128 + jo * 8 + (t >> 5))) * 64 + ((t * 2) & 63)) = m[0];
  } else if (mb < 227) {
    // weight pack into MFMA B-fragment layout
    int mi = 8;
    while (mi > 0 && mb < g_mBlk0[mi]) --mi;
    const int NT = g_mNT[mi], K = g_mK[mi], N = g_mN[mi], K0 = g_mK0[mi];
    const int L = (mb - g_mBlk0[mi]) * 256 + t;
    const int lanes = ((K + 31) >> 5) * NT * 64;
    if (L < lanes) {
      const int lane = L & 63, tile = L >> 6;
      const int kk = tile / NT, nn = tile % NT;
      const float* src = in.p[g_mSrc[mi]];
      const int n = nn * 16 + (lane & 15);
      const int kb = kk * 32 + ((lane >> 4) << 3);
      f16x8 v;
      #pragma unroll
      for (int u = 0; u < 8; ++u) {
        const int k = kb + u;
        float f = (k < K && n < N) ? src[(size_t)(K0 + k) * N + n] : 0.f;
        v[u] = (f16)f;
      }
      *(f16x8*)(wpk + g_mDst[mi] + (size_t)L * 8) = v;
    }
  } else if (mb < 235) {
    // qmax[b,d] = max_i Q[b,i,d]
    const int b = mb - 227;
    const float* Qb = in.p[1] + (size_t)b * 128 * 128;
    const int d = t & 127, g = t >> 7;
    float m0 = -3.4e38f, m1 = m0, m2 = m0, m3 = m0;
    #pragma unroll
    for (int v = 0; v < 16; ++v) {
      const int i = g * 64 + v * 4;
      m0 = fmaxf(m0, Qb[(size_t)(i + 0) * 128 + d]);
      m1 = fmaxf(m1, Qb[(size_t)(i + 1) * 128 + d]);
      m2 = fmaxf(m2, Qb[(size_t)(i + 2) * 128 + d]);
      m3 = fmaxf(m3, Qb[(size_t)(i + 3) * 128 + d]);
    }
    sbuf[g * 128 + d] = fmaxf(fmaxf(m0, m1), fmaxf(m2, m3));
    __syncthreads();
    if (t < 128) qmax[b * 128 + t] = fmaxf(sbuf[t], sbuf[128 + t]);
  } else if (mb < 243) {
    // e1q[b,n] = P[b] . q_w1[0:128] + q_b1
    const int b = mb - 235;
    const float* P = in.p[0]; const float* qw1 = in.p[9]; const float* qb1 = in.p[10];
    if (t < 160) {
      float a = 0.f;
      if (t < 132) {
        float a0 = 0.f, a1 = 0.f, a2 = 0.f, a3 = 0.f;
        for (int k = 0; k < 128; k += 4) {
          a0 += P[b * 128 + k + 0] * qw1[(size_t)(k + 0) * 132 + t];
          a1 += P[b * 128 + k + 1] * qw1[(size_t)(k + 1) * 132 + t];
          a2 += P[b * 128 + k + 2] * qw1[(size_t)(k + 2) * 132 + t];
          a3 += P[b * 128 + k + 3] * qw1[(size_t)(k + 3) * 132 + t];
        }
        a = qb1[t] + (a0 + a1) + (a2 + a3);
      }
      e1q[b * 160 + t] = a;
    }
  } else if (mb < 499) {
    // c1/d1 (r-branch folded Q contributions), 4 Q-rows per block
    const int blk = mb - 243;
    const float* Q = in.p[1]; const float* rw1 = in.p[15]; const float* rb1 = in.p[16];
    for (int o = t; o < 512; o += 256) sbuf[o] = Q[(size_t)blk * 512 + o];
    __syncthreads();
    if (t < 160) {
      float cc[4], dd[4];
      #pragma unroll
      for (int r = 0; r < 4; ++r) { cc[r] = 0.f; dd[r] = 0.f; }
      if (t < 132) {
        const float bb = rb1[t];
        #pragma unroll
        for (int r = 0; r < 4; ++r) cc[r] = bb;
        for (int k = 0; k < 128; ++k) {
          const float wc = rw1[(size_t)(192 + k) * 132 + t];
          const float wd = rw1[(size_t)(64 + k) * 132 + t];
          #pragma unroll
          for (int r = 0; r < 4; ++r) {
            cc[r] += sbuf[r * 128 + k] * wc;
            dd[r] += sbuf[r * 128 + k] * wd;
          }
        }
      }
      for (int r = 0; r < 4; ++r) {
        c1[(size_t)(blk * 4 + r) * 160 + t] = cc[r];
        d1[(size_t)(blk * 4 + r) * 160 + t] = dd[r];
      }
    }
  } else {
    // red1[b,i,d] = max_j R[b,i,j,d]; one block per (b,i); contiguous loads.
    const int bi = mb - 499;
    const int d2 = t & 31, jg = t >> 5;   // jg in 0..7, 16 j's each
    const float* base = in.p[2] + (size_t)bi * 8192 + (size_t)jg * 1024 + d2 * 2;
    f32x2 m[4];
    #pragma unroll
    for (int u = 0; u < 4; ++u) { m[u][0] = -3.4e38f; m[u][1] = -3.4e38f; }
    #pragma unroll
    for (int v = 0; v < 16; v += 4) {
      #pragma unroll
      for (int u = 0; u < 4; ++u) {
        f32x2 vv = *(const f32x2*)(base + (size_t)(v + u) * 64);
        m[u][0] = fmaxf(m[u][0], vv[0]);
        m[u][1] = fmaxf(m[u][1], vv[1]);
      }
    }
    m[0][0] = fmaxf(fmaxf(m[0][0], m[1][0]), fmaxf(m[2][0], m[3][0]));
    m[0][1] = fmaxf(fmaxf(m[0][1], m[1][1]), fmaxf(m[2][1], m[3][1]));
    sbuf[jg * 64 + d2 * 2] = m[0][0];
    sbuf[jg * 64 + d2 * 2 + 1] = m[0][1];
    __syncthreads();
    if (t < 64) {
      float mm = sbuf[t];
      #pragma unroll
      for (int g2 = 1; g2 < 8; ++g2) mm = fmaxf(mm, sbuf[g2 * 64 + t]);
      red1[(size_t)bi * 64 + t] = mm;
    }
  }
}

__device__ __forceinline__ float sig5(float x) {
  return 1.f / (1.f + __expf(-5.f * x));
}

__device__ __forceinline__ f16x8 ld_frag_f32(const float* p) {
  f32x4 v0 = *(const f32x4*)(p);
  f32x4 v1 = *(const f32x4*)(p + 4);
  f16x8 a;
  a[0] = (f16)v0[0]; a[1] = (f16)v0[1]; a[2] = (f16)v0[2]; a[3] = (f16)v0[3];
  a[4] = (f16)v1[0]; a[5] = (f16)v1[1]; a[6] = (f16)v1[2]; a[7] = (f16)v1[3];
  return a;
}

// ---------------------------------------------------------------------------
// fused kernel: blocks [0,17) = Q/P branch (first -> overlap with R work);
//               blocks [17,2065) = R branch, one per (b,i,j-half), 64 rows.
// Swapped-operand MFMA: D = W^T X^T; lane owns 4 consecutive n for one j.
// LDS = 21.5 KB (H only); A-frags load directly from global (f32->f16).
// launch_bounds(256,4): <=128 VGPR -> 4 blocks/CU resident.
// ---------------------------------------------------------------------------
__global__ __launch_bounds__(256, 4) void fused_kernel(
    const float* __restrict__ R, const float* __restrict__ c1, const float* __restrict__ d1,
    const float* __restrict__ rb2, const float* __restrict__ rb3,
    const f16* __restrict__ wpk, float* __restrict__ outR,
    const float* __restrict__ P, const float* __restrict__ Q,
    const float* __restrict__ qb2, const float* __restrict__ qb3,
    const float* __restrict__ pb1, const float* __restrict__ pb2, const float* __restrict__ pb3,
    const float* __restrict__ e1q, const float* __restrict__ qmax,
    const float* __restrict__ red0, const float* __restrict__ red1,
    float* __restrict__ outP, float* __restrict__ outQ)
{
  __shared__ f16 Hs[64][168];        // 21504 B
  const int blk = blockIdx.x;
  const int t = threadIdx.x, lane = t & 63, w = t >> 6;
  const int wm = w >> 1, wn = w & 1;
  const int lr = (lane >> 4) << 2;   // n-quad within 16-tile (D rows)
  const int lc = lane & 15;          // j within 16-tile (D cols / X row)
  const int lk = (lane >> 4) << 3;   // k offset within frag
  const int rbase = wm * 32, nbase = wn * 80;

  f32x4 acc[2][5];
  const float* b2p;                  // L2 bias
  const float* b3p;                  // L3 bias
  const f16x8* W2p;
  const f16x8* W3p;
  float* obase;                      // out addr = obase + jl*64 + n
  int rowlim;

  if (blk >= 17) {
    // ================= R branch L1 =================
    const int idx = blk - 17;
    const int bi = idx >> 1, half = idx & 1;
    const int jbase = half * 64;
    const int b = bi >> 7;
    const float* Rb = R + (size_t)bi * 8192 + (size_t)jbase * 64;

    const float* c1r = c1 + (size_t)bi * 160;
    const float* d1b = d1 + ((size_t)b * 128 + jbase) * 160;
    f32x4 cvv[5];
    #pragma unroll
    for (int n5 = 0; n5 < 5; ++n5)
      cvv[n5] = *(const f32x4*)(c1r + nbase + n5 * 16 + lr);
    #pragma unroll
    for (int mi2 = 0; mi2 < 2; ++mi2) {
      const int jl = rbase + mi2 * 16 + lc;
      const float* dr = d1b + (size_t)jl * 160 + nbase + lr;
      #pragma unroll
      for (int n5 = 0; n5 < 5; ++n5)
        acc[mi2][n5] = cvv[n5] + *(const f32x4*)(dr + n5 * 16);
    }
    const f16x8* W1p = (const f16x8*)(wpk + OFF_RW1A);
    #pragma unroll
    for (int kk = 0; kk < 2; ++kk) {
      const f16x8 a0 = ld_frag_f32(Rb + (size_t)(rbase + lc) * 64 + kk * 32 + lk);
      const f16x8 a1 = ld_frag_f32(Rb + (size_t)(rbase + 16 + lc) * 64 + kk * 32 + lk);
      #pragma unroll
      for (int n5 = 0; n5 < 5; ++n5) {
        const f16x8 bf = W1p[(size_t)(kk * 10 + wn * 5 + n5) * 64 + lane];
        acc[0][n5] = MFMA16(bf, a0, acc[0][n5]);
        acc[1][n5] = MFMA16(bf, a1, acc[1][n5]);
      }
    }
    b2p = rb2; b3p = rb3;
    W2p = (const f16x8*)(wpk + OFF_RW2);
    W3p = (const f16x8*)(wpk + OFF_RW3);
    obase = outR + (size_t)bi * 8192 + (size_t)jbase * 64;
    rowlim = 64;
  } else {
    // ================= Q / P branch L1 =================
    const int bs = blk;
    const bool isP = (bs == 16);
    const int b = bs >> 1, x0 = (bs & 1) * 64;
    const f16x8* W1p = (const f16x8*)(wpk + (isP ? OFF_PW1 : OFF_QW1));
    const f16x8 zz = {0, 0, 0, 0, 0, 0, 0, 0};

    #pragma unroll
    for (int n5 = 0; n5 < 5; ++n5) {
      const int nb = nbase + n5 * 16 + lr;
      f32x4 cv = {0.f, 0.f, 0.f, 0.f};
      if (isP) { if (nb < 132) cv = *(const f32x4*)(pb1 + nb); }
      else cv = *(const f32x4*)(e1q + b * 160 + nb);
      acc[0][n5] = cv; acc[1][n5] = cv;
    }
    for (int c = 0; c < 4; ++c) {
      #pragma unroll
      for (int kk = 0; kk < 2; ++kk) {
        const int kq = c * 64 + kk * 32 + lk;
        f16x8 a0 = zz, a1 = zz;
        if (isP) {
          #pragma unroll
          for (int mi2 = 0; mi2 < 2; ++mi2) {
            const int rl = rbase + mi2 * 16 + lc;
            f16x8 av = zz;
            if (rl < 8) {
              const float* s = (c < 2) ? (qmax + rl * 128 + kq) : (P + rl * 128 + (kq - 128));
              av = ld_frag_f32(s);
            }
            if (mi2 == 0) a0 = av; else a1 = av;
          }
        } else {
          #pragma unroll
          for (int mi2 = 0; mi2 < 2; ++mi2) {
            const size_t rg = (size_t)(b * 128 + x0 + rbase + mi2 * 16 + lc);
            const float* s = (c < 2) ? (Q + rg * 128 + kq)
                           : ((kq < 192) ? (red0 + rg * 64 + (kq - 128))
                                         : (red1 + rg * 64 + (kq - 192)));
            const f16x8 av = ld_frag_f32(s);
            if (mi2 == 0) a0 = av; else a1 = av;
          }
        }
        #pragma unroll
        for (int n5 = 0; n5 < 5; ++n5) {
          const f16x8 bf = W1p[(size_t)((c * 2 + kk) * 10 + wn * 5 + n5) * 64 + lane];
          acc[0][n5] = MFMA16(bf, a0, acc[0][n5]);
          acc[1][n5] = MFMA16(bf, a1, acc[1][n5]);
        }
      }
    }
    b2p = isP ? pb2 : qb2; b3p = isP ? pb3 : qb3;
    W2p = (const f16x8*)(wpk + (isP ? OFF_PW2 : OFF_QW2));
    W3p = (const f16x8*)(wpk + (isP ? OFF_PW3 : OFF_QW3));
    obase = isP ? outP : (outQ + ((size_t)(b * 128 + x0)) * 64);
    rowlim = isP ? 8 : 64;
  }

  // ---- shared tail: H1 store, L2, H2 store, L3, epilogue ----
  #pragma unroll
  for (int mi2 = 0; mi2 < 2; ++mi2) {
    const int jl = rbase + mi2 * 16 + lc;
    #pragma unroll
    for (int n5 = 0; n5 < 5; ++n5) {
      f16x4 hv;
      #pragma unroll
      for (int r = 0; r < 4; ++r) hv[r] = (f16)fmaxf(acc[mi2][n5][r], 0.f);
      *(f16x4*)(&Hs[jl][nbase + n5 * 16 + lr]) = hv;
    }
  }
  __syncthreads();

  // L2
  #pragma unroll
  for (int n5 = 0; n5 < 5; ++n5) {
    const int nb = nbase + n5 * 16 + lr;
    f32x4 bv = {0.f, 0.f, 0.f, 0.f};
    if (nb < 132) bv = *(const f32x4*)(b2p + nb);
    acc[0][n5] = bv; acc[1][n5] = bv;
  }
  #pragma unroll
  for (int kk = 0; kk < 5; ++kk) {
    const f16x8 a0 = *(const f16x8*)(&Hs[rbase + lc][kk * 32 + lk]);
    const f16x8 a1 = *(const f16x8*)(&Hs[rbase + 16 + lc][kk * 32 + lk]);
    #pragma unroll
    for (int n5 = 0; n5 < 5; ++n5) {
      const f16x8 bf = W2p[(size_t)(kk * 10 + wn * 5 + n5) * 64 + lane];
      acc[0][n5] = MFMA16(bf, a0, acc[0][n5]);
      acc[1][n5] = MFMA16(bf, a1, acc[1][n5]);
    }
  }
  __syncthreads();
  #pragma unroll
  for (int mi2 = 0; mi2 < 2; ++mi2) {
    const int jl = rbase + mi2 * 16 + lc;
    #pragma unroll
    for (int n5 = 0; n5 < 5; ++n5) {
      f16x4 hv;
      #pragma unroll
      for (int r = 0; r < 4; ++r) hv[r] = (f16)fmaxf(acc[mi2][n5][r], 0.f);
      *(f16x4*)(&Hs[jl][nbase + n5 * 16 + lr]) = hv;
    }
  }
  __syncthreads();

  // L3
  f32x4 acc3[2][2];
  const int n3base = wn * 32;
  #pragma unroll
  for (int n2 = 0; n2 < 2; ++n2) {
    const f32x4 bv = *(const f32x4*)(b3p + n3base + n2 * 16 + lr);
    acc3[0][n2] = bv; acc3[1][n2] = bv;
  }
  #pragma unroll
  for (int kk = 0; kk < 5; ++kk) {
    const f16x8 a0 = *(const f16x8*)(&Hs[rbase + lc][kk * 32 + lk]);
    const f16x8 a1 = *(const f16x8*)(&Hs[rbase + 16 + lc][kk * 32 + lk]);
    #pragma unroll
    for (int n2 = 0; n2 < 2; ++n2) {
      const f16x8 bf = W3p[(size_t)(kk * 4 + wn * 2 + n2) * 64 + lane];
      acc3[0][n2] = MFMA16(bf, a0, acc3[0][n2]);
      acc3[1][n2] = MFMA16(bf, a1, acc3[1][n2]);
    }
  }
  #pragma unroll
  for (int mi2 = 0; mi2 < 2; ++mi2) {
    const int jl = rbase + mi2 * 16 + lc;
    if (jl < rowlim) {
      #pragma unroll
      for (int n2 = 0; n2 < 2; ++n2) {
        f32x4 ov;
        #pragma unroll
        for (int r = 0; r < 4; ++r) ov[r] = sig5(acc3[mi2][n2][r]);
        *(f32x4*)(obase + (size_t)jl * 64 + n3base + n2 * 16 + lr) = ov;
      }
    }
  }
}

extern "C" void kernel_launch(void* const* d_in, const int* in_sizes, int n_in,
                              void* d_out, int out_size, void* d_ws, size_t ws_size,
                              hipStream_t stream) {
  (void)in_sizes; (void)n_in; (void)out_size; (void)ws_size;
  InPtrs ip;
  for (int i = 0; i < 21; ++i) ip.p[i] = (const float*)d_in[i];

  char* ws = (char*)d_ws;
  f16* wpk = (f16*)ws;
  float* wsf = (float*)(ws + PACK_BYTES);
  float* c1 = wsf;
  float* d1 = wsf + 163840;
  float* e1q = wsf + 327680;
  float* qmax = wsf + 328960;
  float* red0 = wsf + 329984;
  float* red1 = wsf + 395520;

  float* outP = (float*)d_out;
  float* outQ = outP + 512;
  float* outR = outP + 66048;

  prep_kernel<<<dim3(PREP_BLOCKS), dim3(256), 0, stream>>>(ip, wpk, c1, d1, e1q, qmax, red0, red1);
  fused_kernel<<<dim3(2065), dim3(256), 0, stream>>>((const float*)d_in[2], c1, d1,
      (const float*)d_in[18], (const float*)d_in[20], wpk, outR,
      (const float*)d_in[0], (const float*)d_in[1],
      (const float*)d_in[12], (const float*)d_in[14],
      (const float*)d_in[4], (const float*)d_in[6], (const float*)d_in[8],
      e1q, qmax, red0, red1, outP, outQ);
}